// Round 1
// baseline (980.936 us; speedup 1.0000x reference)
//
#include <hip/hip_runtime.h>

#define NEG_SLOPE 0.2f

// ---------------------------------------------------------------------------
// K0: initialize accumulators. out1[i*128+j] = b1[j]; out2[i*64+j] = b2[j];
//     denom1[N*4] = 0; denom2[N] = 0.
// ---------------------------------------------------------------------------
__global__ void init_kernel(float* __restrict__ denom1, float* __restrict__ out1,
                            const float* __restrict__ b1,
                            float* __restrict__ denom2, float* __restrict__ out2,
                            const float* __restrict__ b2, int N) {
    int i = blockIdx.x * blockDim.x + threadIdx.x;
    if (i < N * 128) out1[i] = b1[i & 127];
    if (i < N * 64)  out2[i] = b2[i & 63];
    if (i < N * 4)   denom1[i] = 0.f;
    if (i < N)       denom2[i] = 0.f;
}

// ---------------------------------------------------------------------------
// K1: feat1 = h @ W1  ([N,128] x [128,128]), fused el1/er1 = sum(feat*attn)
//     One row per block, 128 threads (one output column each).
// ---------------------------------------------------------------------------
__global__ void gemm1_kernel(const float* __restrict__ h, const float* __restrict__ W1,
                             const float* __restrict__ al1, const float* __restrict__ ar1,
                             float* __restrict__ feat1, float* __restrict__ el1,
                             float* __restrict__ er1) {
    const int row = blockIdx.x;
    const int tid = threadIdx.x;  // 0..127
    __shared__ float xs[128];
    xs[tid] = h[row * 128 + tid];
    __syncthreads();
    float acc = 0.f;
#pragma unroll
    for (int k = 0; k < 128; ++k) acc = fmaf(xs[k], W1[k * 128 + tid], acc);
    feat1[row * 128 + tid] = acc;
    // el/er per head: tid = h*32 + d matches al1 flat [4,32] layout
    float pl = acc * al1[tid];
    float pr = acc * ar1[tid];
#pragma unroll
    for (int off = 16; off; off >>= 1) {
        pl += __shfl_xor(pl, off, 32);
        pr += __shfl_xor(pr, off, 32);
    }
    if ((tid & 31) == 0) {
        el1[row * 4 + (tid >> 5)] = pl;
        er1[row * 4 + (tid >> 5)] = pr;
    }
}

// ---------------------------------------------------------------------------
// K4: feat2 = relu(out1) @ W2  ([N,128] x [128,64]), fused el2/er2 ([N,1]).
//     One row per block, 64 threads.
// ---------------------------------------------------------------------------
__global__ void gemm2_kernel(const float* __restrict__ out1, const float* __restrict__ W2,
                             const float* __restrict__ al2, const float* __restrict__ ar2,
                             float* __restrict__ feat2, float* __restrict__ el2,
                             float* __restrict__ er2) {
    const int row = blockIdx.x;
    const int tid = threadIdx.x;  // 0..63
    __shared__ float xs[128];
    float v0 = out1[row * 128 + tid];
    float v1 = out1[row * 128 + 64 + tid];
    xs[tid] = v0 > 0.f ? v0 : 0.f;
    xs[64 + tid] = v1 > 0.f ? v1 : 0.f;
    __syncthreads();
    float acc = 0.f;
#pragma unroll
    for (int k = 0; k < 128; ++k) acc = fmaf(xs[k], W2[k * 64 + tid], acc);
    feat2[row * 64 + tid] = acc;
    float pl = acc * al2[tid];
    float pr = acc * ar2[tid];
#pragma unroll
    for (int off = 32; off; off >>= 1) {
        pl += __shfl_xor(pl, off, 64);
        pr += __shfl_xor(pr, off, 64);
    }
    if (tid == 0) {
        el2[row] = pl;
        er2[row] = pr;
    }
}

// ---------------------------------------------------------------------------
// Edge pass A: a[e,h] = exp(leaky_relu(el[src]+er[dst])); denom[dst,h] += a.
// (max-subtraction dropped: alpha is invariant and |e| stays small)
// ---------------------------------------------------------------------------
__global__ void edgeA_kernel(const int* __restrict__ src, const int* __restrict__ dst,
                             const float* __restrict__ el, const float* __restrict__ er,
                             float* __restrict__ a, float* __restrict__ denom,
                             int E, int H) {
    int e = blockIdx.x * blockDim.x + threadIdx.x;
    if (e >= E) return;
    int s = src[e], d = dst[e];
    for (int h = 0; h < H; ++h) {
        float v = el[s * H + h] + er[d * H + h];
        v = v > 0.f ? v : NEG_SLOPE * v;
        float av = __expf(v);
        a[e * H + h] = av;
        atomicAdd(&denom[d * H + h], av);
    }
}

// ---------------------------------------------------------------------------
// Edge pass B (layer 1): out1[dst, j] += feat1[src, j] * a[e, j>>5]/denom[dst, j>>5]
// one thread per (edge, j), j in [0,128)
// ---------------------------------------------------------------------------
__global__ void edgeB1_kernel(const int* __restrict__ src, const int* __restrict__ dst,
                              const float* __restrict__ a, const float* __restrict__ denom,
                              const float* __restrict__ feat, float* __restrict__ out,
                              int E) {
    int t = blockIdx.x * blockDim.x + threadIdx.x;
    if (t >= E * 128) return;
    int e = t >> 7;
    int j = t & 127;
    int h = j >> 5;
    int s = src[e], d = dst[e];
    float alpha = a[e * 4 + h] / denom[d * 4 + h];
    atomicAdd(&out[d * 128 + j], feat[s * 128 + j] * alpha);
}

// ---------------------------------------------------------------------------
// Edge pass B (layer 2): out[dst, j] += feat2[src, j] * a[e]/denom[dst], j in [0,64)
// ---------------------------------------------------------------------------
__global__ void edgeB2_kernel(const int* __restrict__ src, const int* __restrict__ dst,
                              const float* __restrict__ a, const float* __restrict__ denom,
                              const float* __restrict__ feat, float* __restrict__ out,
                              int E) {
    int t = blockIdx.x * blockDim.x + threadIdx.x;
    if (t >= E * 64) return;
    int e = t >> 6;
    int j = t & 63;
    int s = src[e], d = dst[e];
    float alpha = a[e] / denom[d];
    atomicAdd(&out[d * 64 + j], feat[s * 64 + j] * alpha);
}

extern "C" void kernel_launch(void* const* d_in, const int* in_sizes, int n_in,
                              void* d_out, int out_size, void* d_ws, size_t ws_size,
                              hipStream_t stream) {
    const float* h   = (const float*)d_in[0];
    const int*   src = (const int*)d_in[1];
    const int*   dst = (const int*)d_in[2];
    const float* W1  = (const float*)d_in[3];
    const float* al1 = (const float*)d_in[4];
    const float* ar1 = (const float*)d_in[5];
    const float* b1  = (const float*)d_in[6];
    const float* W2  = (const float*)d_in[7];
    const float* al2 = (const float*)d_in[8];
    const float* ar2 = (const float*)d_in[9];
    const float* b2  = (const float*)d_in[10];

    const int N = in_sizes[0] / 128;  // 50000
    const int E = in_sizes[1];        // 800000

    // workspace carve-up (fp32)
    char* ws = (char*)d_ws;
    size_t off = 0;
    auto alloc = [&](size_t elems) {
        float* p = (float*)(ws + off);
        off += ((elems * 4 + 255) / 256) * 256;
        return p;
    };
    float* feat1  = alloc((size_t)N * 128);
    float* out1   = alloc((size_t)N * 128);
    float* a1     = alloc((size_t)E * 4);
    float* feat2  = alloc((size_t)N * 64);
    float* el1    = alloc((size_t)N * 4);
    float* er1    = alloc((size_t)N * 4);
    float* denom1 = alloc((size_t)N * 4);
    float* el2    = alloc((size_t)N);
    float* er2    = alloc((size_t)N);
    float* denom2 = alloc((size_t)N);
    float* a2     = alloc((size_t)E);

    float* out2 = (float*)d_out;  // [N,64]

    // K0: init accumulators (biases) + zero denominators
    {
        int total = N * 128;
        init_kernel<<<(total + 255) / 256, 256, 0, stream>>>(denom1, out1, b1, denom2,
                                                             out2, b2, N);
    }
    // K1: GEMM1 + el1/er1
    gemm1_kernel<<<N, 128, 0, stream>>>(h, W1, al1, ar1, feat1, el1, er1);
    // K2: edge softmax numerators + denominators (layer 1, H=4)
    edgeA_kernel<<<(E + 255) / 256, 256, 0, stream>>>(src, dst, el1, er1, a1, denom1, E, 4);
    // K3: scatter messages (layer 1)
    {
        long total = (long)E * 128;
        edgeB1_kernel<<<(int)((total + 255) / 256), 256, 0, stream>>>(src, dst, a1, denom1,
                                                                      feat1, out1, E);
    }
    // K4: GEMM2 (relu fused on load) + el2/er2
    gemm2_kernel<<<N, 64, 0, stream>>>(out1, W2, al2, ar2, feat2, el2, er2);
    // K5: edge softmax (layer 2, H=1)
    edgeA_kernel<<<(E + 255) / 256, 256, 0, stream>>>(src, dst, el2, er2, a2, denom2, E, 1);
    // K6: scatter messages (layer 2) -> d_out
    {
        long total = (long)E * 64;
        edgeB2_kernel<<<(int)((total + 255) / 256), 256, 0, stream>>>(src, dst, a2, denom2,
                                                                      feat2, out2, E);
    }
}

// Round 2
// 422.126 us; speedup vs baseline: 2.3238x; 2.3238x over previous
//
#include <hip/hip_runtime.h>

#define NEG_SLOPE 0.2f

// ===========================================================================
// CSR build: counts -> scan -> scatter (src,dst) into dst-sorted slots
// ===========================================================================
__global__ void zero_counts_kernel(int* __restrict__ counts, int N) {
    int i = blockIdx.x * blockDim.x + threadIdx.x;
    if (i < N) counts[i] = 0;
}

__global__ void hist_kernel(const int* __restrict__ dst, int* __restrict__ counts, int E) {
    int e = blockIdx.x * blockDim.x + threadIdx.x;
    if (e < E) atomicAdd(&counts[dst[e]], 1);
}

// per-1024-chunk inclusive scan; writes exclusive results + chunk total
__global__ void scanA_kernel(const int* __restrict__ counts, int* __restrict__ row_excl,
                             int* __restrict__ blocksum, int N) {
    __shared__ int sh[1024];
    int tid = threadIdx.x;
    int i = blockIdx.x * 1024 + tid;
    int v = (i < N) ? counts[i] : 0;
    sh[tid] = v;
    __syncthreads();
    for (int off = 1; off < 1024; off <<= 1) {
        int t = (tid >= off) ? sh[tid - off] : 0;
        __syncthreads();
        sh[tid] += t;
        __syncthreads();
    }
    if (i < N) row_excl[i] = sh[tid] - v;
    if (tid == 1023) blocksum[blockIdx.x] = sh[1023];
}

// scan of block sums (nb <= 64), one wave
__global__ void scanB_kernel(const int* __restrict__ blocksum, int* __restrict__ blockoff,
                             int* __restrict__ row_start, int N, int nb) {
    int tid = threadIdx.x;  // 64 threads
    int v = (tid < nb) ? blocksum[tid] : 0;
    int orig = v;
    for (int off = 1; off < 64; off <<= 1) {
        int t = __shfl_up(v, off, 64);
        if (tid >= off) v += t;
    }
    if (tid < nb) blockoff[tid] = v - orig;
    if (tid == 63) row_start[N] = v;  // = E
}

__global__ void scanC_kernel(int* __restrict__ row_start, int* __restrict__ cursor,
                             const int* __restrict__ row_excl,
                             const int* __restrict__ blockoff, int N) {
    int i = blockIdx.x * blockDim.x + threadIdx.x;
    if (i < N) {
        int v = row_excl[i] + blockoff[i >> 10];
        row_start[i] = v;
        cursor[i] = v;
    }
}

__global__ void scatter_kernel(const int* __restrict__ src, const int* __restrict__ dst,
                               int* __restrict__ cursor, int* __restrict__ srcs,
                               int* __restrict__ dsts, int E) {
    int e = blockIdx.x * blockDim.x + threadIdx.x;
    if (e >= E) return;
    int d = dst[e];
    int pos = atomicAdd(&cursor[d], 1);
    srcs[pos] = src[e];
    dsts[pos] = d;
}

// ===========================================================================
// GEMM1: feat1 = h @ W1  ([N,128]x[128,128]). 32 rows/block, 4x4 per thread.
// ===========================================================================
__global__ __launch_bounds__(256) void gemm1_tiled(const float* __restrict__ h,
                                                   const float* __restrict__ W1,
                                                   float* __restrict__ feat1, int N) {
    __shared__ float xs[32 * 128];
    const int tid = threadIdx.x;
    const int row0 = blockIdx.x * 32;
    {
        const float4* s4 = (const float4*)h;
        float4* d4 = (float4*)xs;
        int base4 = row0 * 32;  // float4 index of block start
        int tot4 = N * 32;
        for (int i = tid; i < 1024; i += 256)
            if (base4 + i < tot4) d4[i] = s4[base4 + i];
    }
    __syncthreads();
    const int c0 = (tid & 31) * 4;
    const int r0 = (tid >> 5) * 4;
    float acc[4][4] = {};
    for (int k = 0; k < 128; ++k) {
        float4 w = *(const float4*)(W1 + k * 128 + c0);
#pragma unroll
        for (int r = 0; r < 4; ++r) {
            float x = xs[(r0 + r) * 128 + k];
            acc[r][0] = fmaf(x, w.x, acc[r][0]);
            acc[r][1] = fmaf(x, w.y, acc[r][1]);
            acc[r][2] = fmaf(x, w.z, acc[r][2]);
            acc[r][3] = fmaf(x, w.w, acc[r][3]);
        }
    }
#pragma unroll
    for (int r = 0; r < 4; ++r) {
        int row = row0 + r0 + r;
        if (row < N)
            *(float4*)(feat1 + (size_t)row * 128 + c0) =
                make_float4(acc[r][0], acc[r][1], acc[r][2], acc[r][3]);
    }
}

// ===========================================================================
// GEMM2: feat2 = relu(out1) @ W2  ([N,128]x[128,64]). 64 rows/block, 4x4/thread.
// ===========================================================================
__global__ __launch_bounds__(256) void gemm2_tiled(const float* __restrict__ out1,
                                                   const float* __restrict__ W2,
                                                   float* __restrict__ feat2, int N) {
    __shared__ float xs[64 * 128];
    const int tid = threadIdx.x;
    const int row0 = blockIdx.x * 64;
    {
        const float4* s4 = (const float4*)out1;
        float4* d4 = (float4*)xs;
        int base4 = row0 * 32;
        int tot4 = N * 32;
        for (int i = tid; i < 2048; i += 256)
            if (base4 + i < tot4) {
                float4 v = s4[base4 + i];
                v.x = v.x > 0.f ? v.x : 0.f;
                v.y = v.y > 0.f ? v.y : 0.f;
                v.z = v.z > 0.f ? v.z : 0.f;
                v.w = v.w > 0.f ? v.w : 0.f;
                d4[i] = v;
            }
    }
    __syncthreads();
    const int c0 = (tid & 15) * 4;
    const int r0 = (tid >> 4) * 4;
    float acc[4][4] = {};
    for (int k = 0; k < 128; ++k) {
        float4 w = *(const float4*)(W2 + k * 64 + c0);
#pragma unroll
        for (int r = 0; r < 4; ++r) {
            float x = xs[(r0 + r) * 128 + k];
            acc[r][0] = fmaf(x, w.x, acc[r][0]);
            acc[r][1] = fmaf(x, w.y, acc[r][1]);
            acc[r][2] = fmaf(x, w.z, acc[r][2]);
            acc[r][3] = fmaf(x, w.w, acc[r][3]);
        }
    }
#pragma unroll
    for (int r = 0; r < 4; ++r) {
        int row = row0 + r0 + r;
        if (row < N)
            *(float4*)(feat2 + (size_t)row * 64 + c0) =
                make_float4(acc[r][0], acc[r][1], acc[r][2], acc[r][3]);
    }
}

// ===========================================================================
// el/er attention dot products
// ===========================================================================
__global__ void elr1_kernel(const float* __restrict__ feat1, const float* __restrict__ al1,
                            const float* __restrict__ ar1, float* __restrict__ el1,
                            float* __restrict__ er1) {
    int row = blockIdx.x;
    int tid = threadIdx.x;  // 128
    float f = feat1[(size_t)row * 128 + tid];
    float pl = f * al1[tid];
    float pr = f * ar1[tid];
#pragma unroll
    for (int off = 16; off; off >>= 1) {
        pl += __shfl_xor(pl, off, 32);
        pr += __shfl_xor(pr, off, 32);
    }
    if ((tid & 31) == 0) {
        el1[row * 4 + (tid >> 5)] = pl;
        er1[row * 4 + (tid >> 5)] = pr;
    }
}

__global__ void elr2_kernel(const float* __restrict__ feat2, const float* __restrict__ al2,
                            const float* __restrict__ ar2, float* __restrict__ el2,
                            float* __restrict__ er2) {
    int row = blockIdx.x;
    int tid = threadIdx.x;  // 64
    float f = feat2[(size_t)row * 64 + tid];
    float pl = f * al2[tid];
    float pr = f * ar2[tid];
#pragma unroll
    for (int off = 32; off; off >>= 1) {
        pl += __shfl_xor(pl, off, 64);
        pr += __shfl_xor(pr, off, 64);
    }
    if (tid == 0) {
        el2[row] = pl;
        er2[row] = pr;
    }
}

// ===========================================================================
// Edge numerators (on dst-sorted edge slots)
// ===========================================================================
__global__ void edgeA1s_kernel(const int* __restrict__ srcs, const int* __restrict__ dsts,
                               const float* __restrict__ el1, const float* __restrict__ er1,
                               float* __restrict__ a1s, int E) {
    int k = blockIdx.x * blockDim.x + threadIdx.x;
    if (k >= E) return;
    int s = srcs[k], d = dsts[k];
    float4 l = *(const float4*)(el1 + s * 4);
    float4 r = *(const float4*)(er1 + d * 4);
    float4 o;
    float v;
    v = l.x + r.x; v = v > 0.f ? v : NEG_SLOPE * v; o.x = __expf(v);
    v = l.y + r.y; v = v > 0.f ? v : NEG_SLOPE * v; o.y = __expf(v);
    v = l.z + r.z; v = v > 0.f ? v : NEG_SLOPE * v; o.z = __expf(v);
    v = l.w + r.w; v = v > 0.f ? v : NEG_SLOPE * v; o.w = __expf(v);
    *(float4*)(a1s + (size_t)k * 4) = o;
}

__global__ void edgeA2s_kernel(const int* __restrict__ srcs, const int* __restrict__ dsts,
                               const float* __restrict__ el2, const float* __restrict__ er2,
                               float* __restrict__ a2s, int E) {
    int k = blockIdx.x * blockDim.x + threadIdx.x;
    if (k >= E) return;
    float v = el2[srcs[k]] + er2[dsts[k]];
    v = v > 0.f ? v : NEG_SLOPE * v;
    a2s[k] = __expf(v);
}

// ===========================================================================
// Gather layer 1: one block (128 thr) per dst node.
// out1[d,j] = b1[j] + sum_e feat1[src_e, j] * a1s[e, j>>5] / denom[d, j>>5]
// ===========================================================================
__global__ void gather1_kernel(const int* __restrict__ row_start, const int* __restrict__ srcs,
                               const float* __restrict__ a1s, const float* __restrict__ feat1,
                               const float* __restrict__ b1, float* __restrict__ out1) {
    const int d = blockIdx.x;
    const int tid = threadIdx.x;  // 128
    const int beg = row_start[d], end = row_start[d + 1];
    __shared__ float red[128];
    // phase 1: per-head denominators (thread t always hits head t&3)
    float p = 0.f;
    for (int k = beg * 4 + tid; k < end * 4; k += 128) p += a1s[k];
    red[tid] = p;
    __syncthreads();
#pragma unroll
    for (int s = 64; s >= 4; s >>= 1) {
        if (tid < s) red[tid] += red[tid + s];
        __syncthreads();
    }
    __shared__ float denom_sh[4];
    if (tid < 4) denom_sh[tid] = red[tid];
    __syncthreads();
    // phase 2: weighted feature sum
    float acc = 0.f;
    const int h = tid >> 5;
    for (int k = beg; k < end; ++k) {
        int s = srcs[k];
        float av = a1s[(size_t)k * 4 + h];
        acc = fmaf(feat1[(size_t)s * 128 + tid], av, acc);
    }
    float o = (end > beg) ? acc / denom_sh[h] : 0.f;
    out1[(size_t)d * 128 + tid] = o + b1[tid];
}

// ===========================================================================
// Gather layer 2: one block (64 thr) per dst node. H=1, D=64.
// ===========================================================================
__global__ void gather2_kernel(const int* __restrict__ row_start, const int* __restrict__ srcs,
                               const float* __restrict__ a2s, const float* __restrict__ feat2,
                               const float* __restrict__ b2, float* __restrict__ out2) {
    const int d = blockIdx.x;
    const int tid = threadIdx.x;  // 64
    const int beg = row_start[d], end = row_start[d + 1];
    float p = 0.f;
    for (int k = beg + tid; k < end; k += 64) p += a2s[k];
#pragma unroll
    for (int off = 32; off; off >>= 1) p += __shfl_xor(p, off, 64);
    float acc = 0.f;
    for (int k = beg; k < end; ++k) {
        int s = srcs[k];
        acc = fmaf(feat2[(size_t)s * 64 + tid], a2s[k], acc);
    }
    float o = (end > beg) ? acc / p : 0.f;
    out2[(size_t)d * 64 + tid] = o + b2[tid];
}

// ===========================================================================
extern "C" void kernel_launch(void* const* d_in, const int* in_sizes, int n_in,
                              void* d_out, int out_size, void* d_ws, size_t ws_size,
                              hipStream_t stream) {
    const float* h   = (const float*)d_in[0];
    const int*   src = (const int*)d_in[1];
    const int*   dst = (const int*)d_in[2];
    const float* W1  = (const float*)d_in[3];
    const float* al1 = (const float*)d_in[4];
    const float* ar1 = (const float*)d_in[5];
    const float* b1  = (const float*)d_in[6];
    const float* W2  = (const float*)d_in[7];
    const float* al2 = (const float*)d_in[8];
    const float* ar2 = (const float*)d_in[9];
    const float* b2  = (const float*)d_in[10];

    const int N = in_sizes[0] / 128;  // 50000
    const int E = in_sizes[1];        // 800000

    char* ws = (char*)d_ws;
    size_t off = 0;
    auto alloc = [&](size_t elems) -> void* {
        void* p = (void*)(ws + off);
        off += ((elems * 4 + 255) / 256) * 256;
        return p;
    };
    int* counts    = (int*)alloc(N);
    int* row_excl  = (int*)alloc(N);
    int* row_start = (int*)alloc(N + 1);
    int* cursor    = (int*)alloc(N);
    int* blocksum  = (int*)alloc(64);
    int* blockoff  = (int*)alloc(64);
    int* srcs      = (int*)alloc(E);
    int* dsts      = (int*)alloc(E);
    float* el1   = (float*)alloc((size_t)N * 4);
    float* er1   = (float*)alloc((size_t)N * 4);
    float* a1s   = (float*)alloc((size_t)E * 4);
    float* feat1 = (float*)alloc((size_t)N * 128);
    float* out1  = (float*)alloc((size_t)N * 128);
    float* el2   = (float*)alloc(N);
    float* er2   = (float*)alloc(N);
    float* a2s   = (float*)alloc(E);
    float* feat2 = (float*)alloc((size_t)N * 64);
    float* out2  = (float*)d_out;

    const int nb = (N + 1023) / 1024;  // scan chunks

    // --- CSR build (shared by both layers) ---
    zero_counts_kernel<<<(N + 255) / 256, 256, 0, stream>>>(counts, N);
    hist_kernel<<<(E + 255) / 256, 256, 0, stream>>>(dst, counts, E);
    scanA_kernel<<<nb, 1024, 0, stream>>>(counts, row_excl, blocksum, N);
    scanB_kernel<<<1, 64, 0, stream>>>(blocksum, blockoff, row_start, N, nb);
    scanC_kernel<<<(N + 255) / 256, 256, 0, stream>>>(row_start, cursor, row_excl, blockoff, N);
    scatter_kernel<<<(E + 255) / 256, 256, 0, stream>>>(src, dst, cursor, srcs, dsts, E);

    // --- layer 1 ---
    gemm1_tiled<<<(N + 31) / 32, 256, 0, stream>>>(h, W1, feat1, N);
    elr1_kernel<<<N, 128, 0, stream>>>(feat1, al1, ar1, el1, er1);
    edgeA1s_kernel<<<(E + 255) / 256, 256, 0, stream>>>(srcs, dsts, el1, er1, a1s, E);
    gather1_kernel<<<N, 128, 0, stream>>>(row_start, srcs, a1s, feat1, b1, out1);

    // --- layer 2 ---
    gemm2_tiled<<<(N + 63) / 64, 256, 0, stream>>>(out1, W2, feat2, N);
    elr2_kernel<<<N, 64, 0, stream>>>(feat2, al2, ar2, el2, er2);
    edgeA2s_kernel<<<(E + 255) / 256, 256, 0, stream>>>(srcs, dsts, el2, er2, a2s, E);
    gather2_kernel<<<N, 64, 0, stream>>>(row_start, srcs, a2s, feat2, b2, out2);
}

// Round 3
// 329.914 us; speedup vs baseline: 2.9733x; 1.2795x over previous
//
#include <hip/hip_runtime.h>

#define NEG_SLOPE 0.2f

__device__ inline unsigned short f2bf(float f) {
    unsigned u = __float_as_uint(f);
    unsigned r = (u + 0x7FFFu + ((u >> 16) & 1u)) >> 16;
    return (unsigned short)r;
}
__device__ inline float bf2f(unsigned short s) {
    return __uint_as_float(((unsigned)s) << 16);
}

// ===========================================================================
// CSR build: counts -> scan -> scatter (src,dst) into dst-sorted slots
// ===========================================================================
__global__ void zero_counts_kernel(int* __restrict__ counts, int N) {
    int i = blockIdx.x * blockDim.x + threadIdx.x;
    if (i < N) counts[i] = 0;
}

__global__ void hist_kernel(const int* __restrict__ dst, int* __restrict__ counts, int E) {
    int e = blockIdx.x * blockDim.x + threadIdx.x;
    if (e < E) atomicAdd(&counts[dst[e]], 1);
}

__global__ void scanA_kernel(const int* __restrict__ counts, int* __restrict__ row_excl,
                             int* __restrict__ blocksum, int N) {
    __shared__ int sh[1024];
    int tid = threadIdx.x;
    int i = blockIdx.x * 1024 + tid;
    int v = (i < N) ? counts[i] : 0;
    sh[tid] = v;
    __syncthreads();
    for (int off = 1; off < 1024; off <<= 1) {
        int t = (tid >= off) ? sh[tid - off] : 0;
        __syncthreads();
        sh[tid] += t;
        __syncthreads();
    }
    if (i < N) row_excl[i] = sh[tid] - v;
    if (tid == 1023) blocksum[blockIdx.x] = sh[1023];
}

__global__ void scanB_kernel(const int* __restrict__ blocksum, int* __restrict__ blockoff,
                             int* __restrict__ row_start, int N, int nb) {
    int tid = threadIdx.x;  // 64 threads
    int v = (tid < nb) ? blocksum[tid] : 0;
    int orig = v;
    for (int off = 1; off < 64; off <<= 1) {
        int t = __shfl_up(v, off, 64);
        if (tid >= off) v += t;
    }
    if (tid < nb) blockoff[tid] = v - orig;
    if (tid == 63) row_start[N] = v;  // = E
}

__global__ void scanC_kernel(int* __restrict__ row_start, int* __restrict__ cursor,
                             const int* __restrict__ row_excl,
                             const int* __restrict__ blockoff, int N) {
    int i = blockIdx.x * blockDim.x + threadIdx.x;
    if (i < N) {
        int v = row_excl[i] + blockoff[i >> 10];
        row_start[i] = v;
        cursor[i] = v;
    }
}

__global__ void scatter_kernel(const int* __restrict__ src, const int* __restrict__ dst,
                               int* __restrict__ cursor, int* __restrict__ srcs,
                               int* __restrict__ dsts, int E) {
    int e = blockIdx.x * blockDim.x + threadIdx.x;
    if (e >= E) return;
    int d = dst[e];
    int pos = atomicAdd(&cursor[d], 1);
    srcs[pos] = src[e];
    dsts[pos] = d;
}

// ===========================================================================
// GEMM1 fused: feat1b(bf16) = h @ W1; el1/er1 from fp32 accumulators.
// 32 rows/block, 256 threads, 4x4 per thread. lane=(tid&31) covers cols.
// ===========================================================================
__global__ __launch_bounds__(256) void gemm1_fused(const float* __restrict__ h,
                                                   const float* __restrict__ W1,
                                                   const float* __restrict__ al1,
                                                   const float* __restrict__ ar1,
                                                   unsigned short* __restrict__ feat1b,
                                                   float* __restrict__ el1,
                                                   float* __restrict__ er1, int N) {
    __shared__ float xs[32 * 128];
    const int tid = threadIdx.x;
    const int row0 = blockIdx.x * 32;
    {
        const float4* s4 = (const float4*)h;
        float4* d4 = (float4*)xs;
        int base4 = row0 * 32;
        int tot4 = N * 32;
        for (int i = tid; i < 1024; i += 256)
            if (base4 + i < tot4) d4[i] = s4[base4 + i];
    }
    __syncthreads();
    const int lane = tid & 31;
    const int c0 = lane * 4;
    const int r0 = (tid >> 5) * 4;
    float acc[4][4] = {};
    for (int k = 0; k < 128; ++k) {
        float4 w = *(const float4*)(W1 + k * 128 + c0);
#pragma unroll
        for (int r = 0; r < 4; ++r) {
            float x = xs[(r0 + r) * 128 + k];
            acc[r][0] = fmaf(x, w.x, acc[r][0]);
            acc[r][1] = fmaf(x, w.y, acc[r][1]);
            acc[r][2] = fmaf(x, w.z, acc[r][2]);
            acc[r][3] = fmaf(x, w.w, acc[r][3]);
        }
    }
    float4 alv = *(const float4*)(al1 + c0);
    float4 arv = *(const float4*)(ar1 + c0);
#pragma unroll
    for (int r = 0; r < 4; ++r) {
        int row = row0 + r0 + r;
        if (row < N) {
            ushort4 fb;
            fb.x = f2bf(acc[r][0]);
            fb.y = f2bf(acc[r][1]);
            fb.z = f2bf(acc[r][2]);
            fb.w = f2bf(acc[r][3]);
            *(ushort4*)(feat1b + (size_t)row * 128 + c0) = fb;
            float pl = acc[r][0] * alv.x + acc[r][1] * alv.y + acc[r][2] * alv.z +
                       acc[r][3] * alv.w;
            float pr = acc[r][0] * arv.x + acc[r][1] * arv.y + acc[r][2] * arv.z +
                       acc[r][3] * arv.w;
            // reduce within 8-lane groups (one head each: head = lane>>3)
#pragma unroll
            for (int off = 4; off >= 1; off >>= 1) {
                pl += __shfl_xor(pl, off, 32);
                pr += __shfl_xor(pr, off, 32);
            }
            if ((lane & 7) == 0) {
                el1[row * 4 + (lane >> 3)] = pl;
                er1[row * 4 + (lane >> 3)] = pr;
            }
        }
    }
}

// ===========================================================================
// GEMM2 fused: feat2(fp32) = relu(out1) @ W2; el2/er2 fused.
// 64 rows/block, 256 threads, 4x4 per thread. 16 lanes cover 64 cols.
// ===========================================================================
__global__ __launch_bounds__(256) void gemm2_fused(const float* __restrict__ out1,
                                                   const float* __restrict__ W2,
                                                   const float* __restrict__ al2,
                                                   const float* __restrict__ ar2,
                                                   float* __restrict__ feat2,
                                                   float* __restrict__ el2,
                                                   float* __restrict__ er2, int N) {
    __shared__ float xs[64 * 128];
    const int tid = threadIdx.x;
    const int row0 = blockIdx.x * 64;
    {
        const float4* s4 = (const float4*)out1;
        float4* d4 = (float4*)xs;
        int base4 = row0 * 32;
        int tot4 = N * 32;
        for (int i = tid; i < 2048; i += 256)
            if (base4 + i < tot4) {
                float4 v = s4[base4 + i];
                v.x = v.x > 0.f ? v.x : 0.f;
                v.y = v.y > 0.f ? v.y : 0.f;
                v.z = v.z > 0.f ? v.z : 0.f;
                v.w = v.w > 0.f ? v.w : 0.f;
                d4[i] = v;
            }
    }
    __syncthreads();
    const int lane = tid & 15;
    const int c0 = lane * 4;
    const int r0 = (tid >> 4) * 4;
    float acc[4][4] = {};
    for (int k = 0; k < 128; ++k) {
        float4 w = *(const float4*)(W2 + k * 64 + c0);
#pragma unroll
        for (int r = 0; r < 4; ++r) {
            float x = xs[(r0 + r) * 128 + k];
            acc[r][0] = fmaf(x, w.x, acc[r][0]);
            acc[r][1] = fmaf(x, w.y, acc[r][1]);
            acc[r][2] = fmaf(x, w.z, acc[r][2]);
            acc[r][3] = fmaf(x, w.w, acc[r][3]);
        }
    }
    float4 alv = *(const float4*)(al2 + c0);
    float4 arv = *(const float4*)(ar2 + c0);
#pragma unroll
    for (int r = 0; r < 4; ++r) {
        int row = row0 + r0 + r;
        if (row < N) {
            *(float4*)(feat2 + (size_t)row * 64 + c0) =
                make_float4(acc[r][0], acc[r][1], acc[r][2], acc[r][3]);
            float pl = acc[r][0] * alv.x + acc[r][1] * alv.y + acc[r][2] * alv.z +
                       acc[r][3] * alv.w;
            float pr = acc[r][0] * arv.x + acc[r][1] * arv.y + acc[r][2] * arv.z +
                       acc[r][3] * arv.w;
#pragma unroll
            for (int off = 8; off >= 1; off >>= 1) {
                pl += __shfl_xor(pl, off, 16);
                pr += __shfl_xor(pr, off, 16);
            }
            if (lane == 0) {
                el2[row] = pl;
                er2[row] = pr;
            }
        }
    }
}

// ===========================================================================
// Edge numerators (dst-sorted slots)
// ===========================================================================
__global__ void edgeA1s_kernel(const int* __restrict__ srcs, const int* __restrict__ dsts,
                               const float* __restrict__ el1, const float* __restrict__ er1,
                               float* __restrict__ a1s, int E) {
    int k = blockIdx.x * blockDim.x + threadIdx.x;
    if (k >= E) return;
    int s = srcs[k], d = dsts[k];
    float4 l = *(const float4*)(el1 + s * 4);
    float4 r = *(const float4*)(er1 + d * 4);
    float4 o;
    float v;
    v = l.x + r.x; v = v > 0.f ? v : NEG_SLOPE * v; o.x = __expf(v);
    v = l.y + r.y; v = v > 0.f ? v : NEG_SLOPE * v; o.y = __expf(v);
    v = l.z + r.z; v = v > 0.f ? v : NEG_SLOPE * v; o.z = __expf(v);
    v = l.w + r.w; v = v > 0.f ? v : NEG_SLOPE * v; o.w = __expf(v);
    *(float4*)(a1s + (size_t)k * 4) = o;
}

__global__ void edgeA2s_kernel(const int* __restrict__ srcs, const int* __restrict__ dsts,
                               const float* __restrict__ el2, const float* __restrict__ er2,
                               float* __restrict__ a2s, int E) {
    int k = blockIdx.x * blockDim.x + threadIdx.x;
    if (k >= E) return;
    float v = el2[srcs[k]] + er2[dsts[k]];
    v = v > 0.f ? v : NEG_SLOPE * v;
    a2s[k] = __expf(v);
}

// ===========================================================================
// Gather layer 1: one wave (64 thr) per dst node, 2 cols/thread, bf16 feat.
// ===========================================================================
__global__ __launch_bounds__(64) void gather1_kernel(const int* __restrict__ row_start,
                                                     const int* __restrict__ srcs,
                                                     const float* __restrict__ a1s,
                                                     const unsigned short* __restrict__ feat1b,
                                                     const float* __restrict__ b1,
                                                     float* __restrict__ out1) {
    const int d = blockIdx.x;
    const int tid = threadIdx.x;  // 0..63
    const int beg = row_start[d], end = row_start[d + 1];
    // phase 1: per-head denominators. position (beg*4 + tid + 64*j) mod 4 == tid&3
    float p = 0.f;
    for (int k = beg * 4 + tid; k < end * 4; k += 64) p += a1s[k];
#pragma unroll
    for (int off = 32; off >= 4; off >>= 1) p += __shfl_xor(p, off, 64);
    const int h = tid >> 4;  // head of this thread's columns
    float denom = __shfl(p, h, 64);
    const int c = tid * 2;
    float acc0 = 0.f, acc1 = 0.f, bcc0 = 0.f, bcc1 = 0.f;
    int k = beg;
    for (; k + 1 < end; k += 2) {
        int s0 = srcs[k], s1 = srcs[k + 1];
        float a0 = a1s[(size_t)k * 4 + h];
        float a1v = a1s[(size_t)(k + 1) * 4 + h];
        ushort2 f0 = *(const ushort2*)(feat1b + (size_t)s0 * 128 + c);
        ushort2 f1 = *(const ushort2*)(feat1b + (size_t)s1 * 128 + c);
        acc0 = fmaf(bf2f(f0.x), a0, acc0);
        acc1 = fmaf(bf2f(f0.y), a0, acc1);
        bcc0 = fmaf(bf2f(f1.x), a1v, bcc0);
        bcc1 = fmaf(bf2f(f1.y), a1v, bcc1);
    }
    if (k < end) {
        int s0 = srcs[k];
        float a0 = a1s[(size_t)k * 4 + h];
        ushort2 f0 = *(const ushort2*)(feat1b + (size_t)s0 * 128 + c);
        acc0 = fmaf(bf2f(f0.x), a0, acc0);
        acc1 = fmaf(bf2f(f0.y), a0, acc1);
    }
    acc0 += bcc0;
    acc1 += bcc1;
    float inv = (end > beg) ? 1.f / denom : 0.f;
    *(float2*)(out1 + (size_t)d * 128 + c) =
        make_float2(acc0 * inv + b1[c], acc1 * inv + b1[c + 1]);
}

// ===========================================================================
// Gather layer 2: one wave per dst node. H=1, D=64, fp32 feat.
// ===========================================================================
__global__ __launch_bounds__(64) void gather2_kernel(const int* __restrict__ row_start,
                                                     const int* __restrict__ srcs,
                                                     const float* __restrict__ a2s,
                                                     const float* __restrict__ feat2,
                                                     const float* __restrict__ b2,
                                                     float* __restrict__ out2) {
    const int d = blockIdx.x;
    const int tid = threadIdx.x;  // 0..63
    const int beg = row_start[d], end = row_start[d + 1];
    float p = 0.f;
    for (int k = beg + tid; k < end; k += 64) p += a2s[k];
#pragma unroll
    for (int off = 32; off; off >>= 1) p += __shfl_xor(p, off, 64);
    float acc0 = 0.f, acc1 = 0.f;
    int k = beg;
    for (; k + 1 < end; k += 2) {
        int s0 = srcs[k], s1 = srcs[k + 1];
        float a0 = a2s[k], a1v = a2s[k + 1];
        acc0 = fmaf(feat2[(size_t)s0 * 64 + tid], a0, acc0);
        acc1 = fmaf(feat2[(size_t)s1 * 64 + tid], a1v, acc1);
    }
    if (k < end) acc0 = fmaf(feat2[(size_t)srcs[k] * 64 + tid], a2s[k], acc0);
    acc0 += acc1;
    float inv = (end > beg) ? 1.f / p : 0.f;
    out2[(size_t)d * 64 + tid] = acc0 * inv + b2[tid];
}

// ===========================================================================
extern "C" void kernel_launch(void* const* d_in, const int* in_sizes, int n_in,
                              void* d_out, int out_size, void* d_ws, size_t ws_size,
                              hipStream_t stream) {
    const float* h   = (const float*)d_in[0];
    const int*   src = (const int*)d_in[1];
    const int*   dst = (const int*)d_in[2];
    const float* W1  = (const float*)d_in[3];
    const float* al1 = (const float*)d_in[4];
    const float* ar1 = (const float*)d_in[5];
    const float* b1  = (const float*)d_in[6];
    const float* W2  = (const float*)d_in[7];
    const float* al2 = (const float*)d_in[8];
    const float* ar2 = (const float*)d_in[9];
    const float* b2  = (const float*)d_in[10];

    const int N = in_sizes[0] / 128;  // 50000
    const int E = in_sizes[1];        // 800000

    char* ws = (char*)d_ws;
    size_t off = 0;
    auto alloc = [&](size_t elems) -> void* {  // elems are 4-byte units
        void* p = (void*)(ws + off);
        off += ((elems * 4 + 255) / 256) * 256;
        return p;
    };
    int* counts    = (int*)alloc(N);
    int* row_excl  = (int*)alloc(N);
    int* row_start = (int*)alloc(N + 1);
    int* cursor    = (int*)alloc(N);
    int* blocksum  = (int*)alloc(64);
    int* blockoff  = (int*)alloc(64);
    int* srcs      = (int*)alloc(E);
    int* dsts      = (int*)alloc(E);
    float* el1   = (float*)alloc((size_t)N * 4);
    float* er1   = (float*)alloc((size_t)N * 4);
    float* a1s   = (float*)alloc((size_t)E * 4);
    unsigned short* feat1b = (unsigned short*)alloc((size_t)N * 64);  // N*128 bf16
    float* out1  = (float*)alloc((size_t)N * 128);
    float* el2   = (float*)alloc(N);
    float* er2   = (float*)alloc(N);
    float* a2s   = (float*)alloc(E);
    float* feat2 = (float*)alloc((size_t)N * 64);
    float* out2  = (float*)d_out;

    const int nb = (N + 1023) / 1024;

    // --- CSR build ---
    zero_counts_kernel<<<(N + 255) / 256, 256, 0, stream>>>(counts, N);
    hist_kernel<<<(E + 255) / 256, 256, 0, stream>>>(dst, counts, E);
    scanA_kernel<<<nb, 1024, 0, stream>>>(counts, row_excl, blocksum, N);
    scanB_kernel<<<1, 64, 0, stream>>>(blocksum, blockoff, row_start, N, nb);
    scanC_kernel<<<(N + 255) / 256, 256, 0, stream>>>(row_start, cursor, row_excl, blockoff, N);
    scatter_kernel<<<(E + 255) / 256, 256, 0, stream>>>(src, dst, cursor, srcs, dsts, E);

    // --- layer 1 ---
    gemm1_fused<<<(N + 31) / 32, 256, 0, stream>>>(h, W1, al1, ar1, feat1b, el1, er1, N);
    edgeA1s_kernel<<<(E + 255) / 256, 256, 0, stream>>>(srcs, dsts, el1, er1, a1s, E);
    gather1_kernel<<<N, 64, 0, stream>>>(row_start, srcs, a1s, feat1b, b1, out1);

    // --- layer 2 ---
    gemm2_fused<<<(N + 63) / 64, 256, 0, stream>>>(out1, W2, al2, ar2, feat2, el2, er2, N);
    edgeA2s_kernel<<<(E + 255) / 256, 256, 0, stream>>>(srcs, dsts, el2, er2, a2s, E);
    gather2_kernel<<<N, 64, 0, stream>>>(row_start, srcs, a2s, feat2, b2, out2);
}

// Round 4
// 313.390 us; speedup vs baseline: 3.1301x; 1.0527x over previous
//
#include <hip/hip_runtime.h>

#define NEG_SLOPE 0.2f

__device__ inline unsigned short f2bf(float f) {
    unsigned u = __float_as_uint(f);
    unsigned r = (u + 0x7FFFu + ((u >> 16) & 1u)) >> 16;
    return (unsigned short)r;
}
__device__ inline float bf2f(unsigned short s) {
    return __uint_as_float(((unsigned)s) << 16);
}

// ===========================================================================
// CSR build: counts -> scan -> scatter src into dst-sorted slots
// ===========================================================================
__global__ void zero_counts_kernel(int* __restrict__ counts, int N) {
    int i = blockIdx.x * blockDim.x + threadIdx.x;
    if (i < N) counts[i] = 0;
}

__global__ void hist_kernel(const int* __restrict__ dst, int* __restrict__ counts, int E) {
    int e = blockIdx.x * blockDim.x + threadIdx.x;
    if (e < E) atomicAdd(&counts[dst[e]], 1);
}

__global__ void scanA_kernel(const int* __restrict__ counts, int* __restrict__ row_excl,
                             int* __restrict__ blocksum, int N) {
    __shared__ int sh[1024];
    int tid = threadIdx.x;
    int i = blockIdx.x * 1024 + tid;
    int v = (i < N) ? counts[i] : 0;
    sh[tid] = v;
    __syncthreads();
    for (int off = 1; off < 1024; off <<= 1) {
        int t = (tid >= off) ? sh[tid - off] : 0;
        __syncthreads();
        sh[tid] += t;
        __syncthreads();
    }
    if (i < N) row_excl[i] = sh[tid] - v;
    if (tid == 1023) blocksum[blockIdx.x] = sh[1023];
}

__global__ void scanB_kernel(const int* __restrict__ blocksum, int* __restrict__ blockoff,
                             int* __restrict__ row_start, int N, int nb) {
    int tid = threadIdx.x;  // 64 threads
    int v = (tid < nb) ? blocksum[tid] : 0;
    int orig = v;
    for (int off = 1; off < 64; off <<= 1) {
        int t = __shfl_up(v, off, 64);
        if (tid >= off) v += t;
    }
    if (tid < nb) blockoff[tid] = v - orig;
    if (tid == 63) row_start[N] = v;  // = E
}

__global__ void scanC_kernel(int* __restrict__ row_start, int* __restrict__ cursor,
                             const int* __restrict__ row_excl,
                             const int* __restrict__ blockoff, int N) {
    int i = blockIdx.x * blockDim.x + threadIdx.x;
    if (i < N) {
        int v = row_excl[i] + blockoff[i >> 10];
        row_start[i] = v;
        cursor[i] = v;
    }
}

__global__ void scatter_kernel(const int* __restrict__ src, const int* __restrict__ dst,
                               int* __restrict__ cursor, int* __restrict__ srcs, int E) {
    int e = blockIdx.x * blockDim.x + threadIdx.x;
    if (e >= E) return;
    int d = dst[e];
    int pos = atomicAdd(&cursor[d], 1);
    srcs[pos] = src[e];
}

// ===========================================================================
// GEMM1 fused: feat1b(bf16) = h @ W1; el1/er1 from fp32 accumulators.
// 32 rows/block, 256 threads, 4x4 per thread.
// ===========================================================================
__global__ __launch_bounds__(256) void gemm1_fused(const float* __restrict__ h,
                                                   const float* __restrict__ W1,
                                                   const float* __restrict__ al1,
                                                   const float* __restrict__ ar1,
                                                   unsigned short* __restrict__ feat1b,
                                                   float* __restrict__ el1,
                                                   float* __restrict__ er1, int N) {
    __shared__ float xs[32 * 128];
    const int tid = threadIdx.x;
    const int row0 = blockIdx.x * 32;
    {
        const float4* s4 = (const float4*)h;
        float4* d4 = (float4*)xs;
        int base4 = row0 * 32;
        int tot4 = N * 32;
        for (int i = tid; i < 1024; i += 256)
            if (base4 + i < tot4) d4[i] = s4[base4 + i];
    }
    __syncthreads();
    const int lane = tid & 31;
    const int c0 = lane * 4;
    const int r0 = (tid >> 5) * 4;
    float acc[4][4] = {};
    for (int k = 0; k < 128; ++k) {
        float4 w = *(const float4*)(W1 + k * 128 + c0);
#pragma unroll
        for (int r = 0; r < 4; ++r) {
            float x = xs[(r0 + r) * 128 + k];
            acc[r][0] = fmaf(x, w.x, acc[r][0]);
            acc[r][1] = fmaf(x, w.y, acc[r][1]);
            acc[r][2] = fmaf(x, w.z, acc[r][2]);
            acc[r][3] = fmaf(x, w.w, acc[r][3]);
        }
    }
    float4 alv = *(const float4*)(al1 + c0);
    float4 arv = *(const float4*)(ar1 + c0);
#pragma unroll
    for (int r = 0; r < 4; ++r) {
        int row = row0 + r0 + r;
        if (row < N) {
            ushort4 fb;
            fb.x = f2bf(acc[r][0]);
            fb.y = f2bf(acc[r][1]);
            fb.z = f2bf(acc[r][2]);
            fb.w = f2bf(acc[r][3]);
            *(ushort4*)(feat1b + (size_t)row * 128 + c0) = fb;
            float pl = acc[r][0] * alv.x + acc[r][1] * alv.y + acc[r][2] * alv.z +
                       acc[r][3] * alv.w;
            float pr = acc[r][0] * arv.x + acc[r][1] * arv.y + acc[r][2] * arv.z +
                       acc[r][3] * arv.w;
#pragma unroll
            for (int off = 4; off >= 1; off >>= 1) {
                pl += __shfl_xor(pl, off, 32);
                pr += __shfl_xor(pr, off, 32);
            }
            if ((lane & 7) == 0) {
                el1[row * 4 + (lane >> 3)] = pl;
                er1[row * 4 + (lane >> 3)] = pr;
            }
        }
    }
}

// ===========================================================================
// GEMM2 fused: feat2b(bf16) = relu(out1) @ W2; el2/er2 from fp32 accumulators.
// 64 rows/block, 256 threads, 4x4 per thread.
// ===========================================================================
__global__ __launch_bounds__(256) void gemm2_fused(const float* __restrict__ out1,
                                                   const float* __restrict__ W2,
                                                   const float* __restrict__ al2,
                                                   const float* __restrict__ ar2,
                                                   unsigned short* __restrict__ feat2b,
                                                   float* __restrict__ el2,
                                                   float* __restrict__ er2, int N) {
    __shared__ float xs[64 * 128];
    const int tid = threadIdx.x;
    const int row0 = blockIdx.x * 64;
    {
        const float4* s4 = (const float4*)out1;
        float4* d4 = (float4*)xs;
        int base4 = row0 * 32;
        int tot4 = N * 32;
        for (int i = tid; i < 2048; i += 256)
            if (base4 + i < tot4) {
                float4 v = s4[base4 + i];
                v.x = v.x > 0.f ? v.x : 0.f;
                v.y = v.y > 0.f ? v.y : 0.f;
                v.z = v.z > 0.f ? v.z : 0.f;
                v.w = v.w > 0.f ? v.w : 0.f;
                d4[i] = v;
            }
    }
    __syncthreads();
    const int lane = tid & 15;
    const int c0 = lane * 4;
    const int r0 = (tid >> 4) * 4;
    float acc[4][4] = {};
    for (int k = 0; k < 128; ++k) {
        float4 w = *(const float4*)(W2 + k * 64 + c0);
#pragma unroll
        for (int r = 0; r < 4; ++r) {
            float x = xs[(r0 + r) * 128 + k];
            acc[r][0] = fmaf(x, w.x, acc[r][0]);
            acc[r][1] = fmaf(x, w.y, acc[r][1]);
            acc[r][2] = fmaf(x, w.z, acc[r][2]);
            acc[r][3] = fmaf(x, w.w, acc[r][3]);
        }
    }
    float4 alv = *(const float4*)(al2 + c0);
    float4 arv = *(const float4*)(ar2 + c0);
#pragma unroll
    for (int r = 0; r < 4; ++r) {
        int row = row0 + r0 + r;
        if (row < N) {
            ushort4 fb;
            fb.x = f2bf(acc[r][0]);
            fb.y = f2bf(acc[r][1]);
            fb.z = f2bf(acc[r][2]);
            fb.w = f2bf(acc[r][3]);
            *(ushort4*)(feat2b + (size_t)row * 64 + c0) = fb;
            float pl = acc[r][0] * alv.x + acc[r][1] * alv.y + acc[r][2] * alv.z +
                       acc[r][3] * alv.w;
            float pr = acc[r][0] * arv.x + acc[r][1] * arv.y + acc[r][2] * arv.z +
                       acc[r][3] * arv.w;
#pragma unroll
            for (int off = 8; off >= 1; off >>= 1) {
                pl += __shfl_xor(pl, off, 16);
                pr += __shfl_xor(pr, off, 16);
            }
            if (lane == 0) {
                el2[row] = pl;
                er2[row] = pr;
            }
        }
    }
}

// ===========================================================================
// Gather layer 1 (fully fused): one wave per dst; a + denom computed in-loop.
// out1[d,c] = b1[c] + (Σ_e feat1b[s_e,c]·a_e) / (Σ_e a_e),
// a_e = exp(leakyrelu(el1[s_e,h] + er1[d,h]))
// ===========================================================================
__global__ __launch_bounds__(64) void gather1_kernel(const int* __restrict__ row_start,
                                                     const int* __restrict__ srcs,
                                                     const float* __restrict__ el1,
                                                     const float* __restrict__ er1,
                                                     const unsigned short* __restrict__ feat1b,
                                                     const float* __restrict__ b1,
                                                     float* __restrict__ out1) {
    const int d = blockIdx.x;
    const int tid = threadIdx.x;  // 0..63
    const int beg = row_start[d], end = row_start[d + 1];
    const int h = tid >> 4;       // head of this thread's columns
    const float er_d = er1[d * 4 + h];
    const int c = tid * 2;
    float acc0 = 0.f, acc1 = 0.f, bcc0 = 0.f, bcc1 = 0.f;
    float den0 = 0.f, den1 = 0.f;
    int k = beg;
    for (; k + 1 < end; k += 2) {
        int s0 = srcs[k], s1 = srcs[k + 1];
        float v0 = el1[s0 * 4 + h] + er_d;
        float v1 = el1[s1 * 4 + h] + er_d;
        v0 = v0 > 0.f ? v0 : NEG_SLOPE * v0;
        v1 = v1 > 0.f ? v1 : NEG_SLOPE * v1;
        float a0 = __expf(v0);
        float a1 = __expf(v1);
        ushort2 f0 = *(const ushort2*)(feat1b + (size_t)s0 * 128 + c);
        ushort2 f1 = *(const ushort2*)(feat1b + (size_t)s1 * 128 + c);
        den0 += a0;
        den1 += a1;
        acc0 = fmaf(bf2f(f0.x), a0, acc0);
        acc1 = fmaf(bf2f(f0.y), a0, acc1);
        bcc0 = fmaf(bf2f(f1.x), a1, bcc0);
        bcc1 = fmaf(bf2f(f1.y), a1, bcc1);
    }
    if (k < end) {
        int s0 = srcs[k];
        float v0 = el1[s0 * 4 + h] + er_d;
        v0 = v0 > 0.f ? v0 : NEG_SLOPE * v0;
        float a0 = __expf(v0);
        ushort2 f0 = *(const ushort2*)(feat1b + (size_t)s0 * 128 + c);
        den0 += a0;
        acc0 = fmaf(bf2f(f0.x), a0, acc0);
        acc1 = fmaf(bf2f(f0.y), a0, acc1);
    }
    acc0 += bcc0;
    acc1 += bcc1;
    float den = den0 + den1;
    float inv = (end > beg) ? 1.f / den : 0.f;
    *(float2*)(out1 + (size_t)d * 128 + c) =
        make_float2(acc0 * inv + b1[c], acc1 * inv + b1[c + 1]);
}

// ===========================================================================
// Gather layer 2 (fully fused): one wave per dst. H=1, D=64, bf16 feat.
// ===========================================================================
__global__ __launch_bounds__(64) void gather2_kernel(const int* __restrict__ row_start,
                                                     const int* __restrict__ srcs,
                                                     const float* __restrict__ el2,
                                                     const float* __restrict__ er2,
                                                     const unsigned short* __restrict__ feat2b,
                                                     const float* __restrict__ b2,
                                                     float* __restrict__ out2) {
    const int d = blockIdx.x;
    const int tid = threadIdx.x;  // 0..63
    const int beg = row_start[d], end = row_start[d + 1];
    const float er_d = er2[d];
    float acc0 = 0.f, acc1 = 0.f, den0 = 0.f, den1 = 0.f;
    int k = beg;
    for (; k + 1 < end; k += 2) {
        int s0 = srcs[k], s1 = srcs[k + 1];
        float v0 = el2[s0] + er_d;
        float v1 = el2[s1] + er_d;
        v0 = v0 > 0.f ? v0 : NEG_SLOPE * v0;
        v1 = v1 > 0.f ? v1 : NEG_SLOPE * v1;
        float a0 = __expf(v0);
        float a1 = __expf(v1);
        float f0 = bf2f(feat2b[(size_t)s0 * 64 + tid]);
        float f1 = bf2f(feat2b[(size_t)s1 * 64 + tid]);
        den0 += a0;
        den1 += a1;
        acc0 = fmaf(f0, a0, acc0);
        acc1 = fmaf(f1, a1, acc1);
    }
    if (k < end) {
        int s0 = srcs[k];
        float v0 = el2[s0] + er_d;
        v0 = v0 > 0.f ? v0 : NEG_SLOPE * v0;
        float a0 = __expf(v0);
        den0 += a0;
        acc0 = fmaf(bf2f(feat2b[(size_t)s0 * 64 + tid]), a0, acc0);
    }
    acc0 += acc1;
    float den = den0 + den1;
    float inv = (end > beg) ? 1.f / den : 0.f;
    out2[(size_t)d * 64 + tid] = acc0 * inv + b2[tid];
}

// ===========================================================================
extern "C" void kernel_launch(void* const* d_in, const int* in_sizes, int n_in,
                              void* d_out, int out_size, void* d_ws, size_t ws_size,
                              hipStream_t stream) {
    const float* h   = (const float*)d_in[0];
    const int*   src = (const int*)d_in[1];
    const int*   dst = (const int*)d_in[2];
    const float* W1  = (const float*)d_in[3];
    const float* al1 = (const float*)d_in[4];
    const float* ar1 = (const float*)d_in[5];
    const float* b1  = (const float*)d_in[6];
    const float* W2  = (const float*)d_in[7];
    const float* al2 = (const float*)d_in[8];
    const float* ar2 = (const float*)d_in[9];
    const float* b2  = (const float*)d_in[10];

    const int N = in_sizes[0] / 128;  // 50000
    const int E = in_sizes[1];        // 800000

    char* ws = (char*)d_ws;
    size_t off = 0;
    auto alloc = [&](size_t elems) -> void* {  // elems are 4-byte units
        void* p = (void*)(ws + off);
        off += ((elems * 4 + 255) / 256) * 256;
        return p;
    };
    int* counts    = (int*)alloc(N);
    int* row_excl  = (int*)alloc(N);
    int* row_start = (int*)alloc(N + 1);
    int* cursor    = (int*)alloc(N);
    int* blocksum  = (int*)alloc(64);
    int* blockoff  = (int*)alloc(64);
    int* srcs      = (int*)alloc(E);
    float* el1   = (float*)alloc((size_t)N * 4);
    float* er1   = (float*)alloc((size_t)N * 4);
    unsigned short* feat1b = (unsigned short*)alloc((size_t)N * 64);  // N*128 bf16
    float* out1  = (float*)alloc((size_t)N * 128);
    float* el2   = (float*)alloc(N);
    float* er2   = (float*)alloc(N);
    unsigned short* feat2b = (unsigned short*)alloc((size_t)N * 32);  // N*64 bf16
    float* out2  = (float*)d_out;

    const int nb = (N + 1023) / 1024;

    // --- CSR build ---
    zero_counts_kernel<<<(N + 255) / 256, 256, 0, stream>>>(counts, N);
    hist_kernel<<<(E + 255) / 256, 256, 0, stream>>>(dst, counts, E);
    scanA_kernel<<<nb, 1024, 0, stream>>>(counts, row_excl, blocksum, N);
    scanB_kernel<<<1, 64, 0, stream>>>(blocksum, blockoff, row_start, N, nb);
    scanC_kernel<<<(N + 255) / 256, 256, 0, stream>>>(row_start, cursor, row_excl, blockoff, N);
    scatter_kernel<<<(E + 255) / 256, 256, 0, stream>>>(src, dst, cursor, srcs, E);

    // --- layer 1 ---
    gemm1_fused<<<(N + 31) / 32, 256, 0, stream>>>(h, W1, al1, ar1, feat1b, el1, er1, N);
    gather1_kernel<<<N, 64, 0, stream>>>(row_start, srcs, el1, er1, feat1b, b1, out1);

    // --- layer 2 ---
    gemm2_fused<<<(N + 63) / 64, 256, 0, stream>>>(out1, W2, al2, ar2, feat2b, el2, er2, N);
    gather2_kernel<<<N, 64, 0, stream>>>(row_start, srcs, el2, er2, feat2b, b2, out2);
}

// Round 5
// 254.662 us; speedup vs baseline: 3.8519x; 1.2306x over previous
//
#include <hip/hip_runtime.h>

#define NEG_SLOPE 0.2f
#define CH 4096      // edges per partition block
#define DCAP 2048    // max edges per bucket handled via LDS fast path

__device__ inline unsigned short f2bf(float f) {
    unsigned u = __float_as_uint(f);
    unsigned r = (u + 0x7FFFu + ((u >> 16) & 1u)) >> 16;
    return (unsigned short)r;
}
__device__ inline float bf2f(unsigned short s) {
    return __uint_as_float(((unsigned)s) << 16);
}

// ===========================================================================
// CSR build via write-combined radix partition. bucket = dst>>6 (64 dsts each).
// Packed edge: (bucket<<22) | ((dst&63)<<16) | src   (requires N <= 65536)
// ===========================================================================
__global__ void zerob_kernel(int* __restrict__ p, int n) {
    int i = blockIdx.x * blockDim.x + threadIdx.x;
    if (i < n) p[i] = 0;
}

__global__ __launch_bounds__(256) void bucketA_kernel(const int* __restrict__ dst,
                                                      int* __restrict__ bucket_cnt,
                                                      int E, int NB) {
    __shared__ int lh[1024];
    const int tid = threadIdx.x;
    for (int i = tid; i < 1024; i += 256) lh[i] = 0;
    __syncthreads();
    const int base = blockIdx.x * CH;
    const int cnt = min(CH, E - base);
    for (int i = tid; i < cnt; i += 256) atomicAdd(&lh[dst[base + i] >> 6], 1);
    __syncthreads();
    for (int b = tid; b < NB; b += 256)
        if (lh[b]) atomicAdd(&bucket_cnt[b], lh[b]);
}

__global__ __launch_bounds__(1024) void bucketB_kernel(const int* __restrict__ bucket_cnt,
                                                       int* __restrict__ bucket_base,
                                                       int* __restrict__ bucket_cursor,
                                                       int* __restrict__ row_start,
                                                       int N, int NB, int E) {
    __shared__ int sh[1024];
    const int tid = threadIdx.x;
    int v = (tid < NB) ? bucket_cnt[tid] : 0;
    sh[tid] = v;
    __syncthreads();
    for (int off = 1; off < 1024; off <<= 1) {
        int t = (tid >= off) ? sh[tid - off] : 0;
        __syncthreads();
        sh[tid] += t;
        __syncthreads();
    }
    int ex = sh[tid] - v;
    if (tid < NB) {
        bucket_base[tid] = ex;
        bucket_cursor[tid] = ex;
    }
    if (tid == NB - 1) bucket_base[NB] = ex + v;  // == E
    if (tid == 0) row_start[N] = E;
}

__global__ __launch_bounds__(256) void bucketC_kernel(const int* __restrict__ src,
                                                      const int* __restrict__ dst,
                                                      int* __restrict__ bucket_cursor,
                                                      unsigned* __restrict__ tmp,
                                                      int E, int NB) {
    __shared__ int lh[1024];        // per-bucket counts (padded to 1024)
    __shared__ int lex[1024];       // per-bucket exclusive prefix
    __shared__ int lcur[1024];      // per-bucket placement cursor
    __shared__ int gbase_sh[1024];  // per-bucket global base for this block
    __shared__ int psum[256];
    __shared__ unsigned sortedv[CH];
    const int tid = threadIdx.x;
    const int base_e = blockIdx.x * CH;
    const int cnt_e = min(CH, E - base_e);
    for (int i = tid; i < 1024; i += 256) lh[i] = 0;
    __syncthreads();
    for (int i = tid; i < cnt_e; i += 256) atomicAdd(&lh[dst[base_e + i] >> 6], 1);
    __syncthreads();
    // block scan over 1024 bucket counts: thread t covers [t*4, t*4+4)
    int s0 = lh[tid * 4], s1 = lh[tid * 4 + 1], s2 = lh[tid * 4 + 2], s3 = lh[tid * 4 + 3];
    int tot = s0 + s1 + s2 + s3;
    psum[tid] = tot;
    __syncthreads();
    for (int off = 1; off < 256; off <<= 1) {
        int t = (tid >= off) ? psum[tid - off] : 0;
        __syncthreads();
        psum[tid] += t;
        __syncthreads();
    }
    int ebase = psum[tid] - tot;
    lex[tid * 4] = ebase;
    lex[tid * 4 + 1] = ebase + s0;
    lex[tid * 4 + 2] = ebase + s0 + s1;
    lex[tid * 4 + 3] = ebase + s0 + s1 + s2;
    __syncthreads();
    // reserve contiguous global runs per bucket
    for (int b = tid; b < NB; b += 256) {
        int c = lh[b];
        gbase_sh[b] = c ? atomicAdd(&bucket_cursor[b], c) : 0;
        lcur[b] = 0;
    }
    __syncthreads();
    // place packed edges into LDS, sorted by bucket
    for (int i = tid; i < cnt_e; i += 256) {
        int e = base_e + i;
        int d = dst[e];
        unsigned b = (unsigned)d >> 6;
        int r = atomicAdd(&lcur[b], 1);
        sortedv[lex[b] + r] = (b << 22) | ((unsigned)(d & 63) << 16) | (unsigned)(src[e] & 0xFFFF);
    }
    __syncthreads();
    // write out: consecutive i within a bucket -> consecutive global addresses
    for (int i = tid; i < cnt_e; i += 256) {
        unsigned v = sortedv[i];
        int b = v >> 22;
        tmp[gbase_sh[b] + (i - lex[b])] = v;
    }
}

__global__ __launch_bounds__(64) void bucketD_kernel(const unsigned* __restrict__ tmp,
                                                     const int* __restrict__ bucket_base,
                                                     int* __restrict__ srcs,
                                                     int* __restrict__ row_start,
                                                     int N, int NB) {
    __shared__ unsigned sval[DCAP];
    __shared__ int ssrc[DCAP];
    __shared__ int dh[64], dex[64], dcur[64];
    const int b = blockIdx.x;
    const int tid = threadIdx.x;  // 0..63 (one wave)
    const int gb = bucket_base[b], ge = bucket_base[b + 1];
    const int cnt = ge - gb;
    dh[tid] = 0;
    __syncthreads();
    if (cnt <= DCAP) {
        for (int i = tid; i < cnt; i += 64) {
            unsigned v = tmp[gb + i];
            sval[i] = v;
            atomicAdd(&dh[(v >> 16) & 63], 1);
        }
        __syncthreads();
        int v = dh[tid], inc = v;
        for (int off = 1; off < 64; off <<= 1) {
            int t = __shfl_up(inc, off, 64);
            if (tid >= off) inc += t;
        }
        int ex = inc - v;
        dex[tid] = ex;
        dcur[tid] = 0;
        __syncthreads();
        for (int i = tid; i < cnt; i += 64) {
            unsigned val = sval[i];
            int dl = (val >> 16) & 63;
            int r = atomicAdd(&dcur[dl], 1);
            ssrc[dex[dl] + r] = (int)(val & 0xFFFFu);
        }
        __syncthreads();
        for (int i = tid; i < cnt; i += 64) srcs[gb + i] = ssrc[i];
        int dglob = b * 64 + tid;
        if (dglob < N) row_start[dglob] = gb + ex;
    } else {
        // robust fallback (never hit for this input): direct global placement
        for (int i = tid; i < cnt; i += 64) atomicAdd(&dh[(tmp[gb + i] >> 16) & 63], 1);
        __syncthreads();
        int v = dh[tid], inc = v;
        for (int off = 1; off < 64; off <<= 1) {
            int t = __shfl_up(inc, off, 64);
            if (tid >= off) inc += t;
        }
        int ex = inc - v;
        dex[tid] = ex;
        dcur[tid] = 0;
        __syncthreads();
        for (int i = tid; i < cnt; i += 64) {
            unsigned val = tmp[gb + i];
            int dl = (val >> 16) & 63;
            int r = atomicAdd(&dcur[dl], 1);
            srcs[gb + dex[dl] + r] = (int)(val & 0xFFFFu);
        }
        int dglob = b * 64 + tid;
        if (dglob < N) row_start[dglob] = gb + ex;
    }
}

// ===========================================================================
// GEMM1 fused: feat1b(bf16) = h @ W1; el1/er1 from fp32 accumulators.
// ===========================================================================
__global__ __launch_bounds__(256) void gemm1_fused(const float* __restrict__ h,
                                                   const float* __restrict__ W1,
                                                   const float* __restrict__ al1,
                                                   const float* __restrict__ ar1,
                                                   unsigned short* __restrict__ feat1b,
                                                   float* __restrict__ el1,
                                                   float* __restrict__ er1, int N) {
    __shared__ float xs[32 * 128];
    const int tid = threadIdx.x;
    const int row0 = blockIdx.x * 32;
    {
        const float4* s4 = (const float4*)h;
        float4* d4 = (float4*)xs;
        int base4 = row0 * 32;
        int tot4 = N * 32;
        for (int i = tid; i < 1024; i += 256)
            if (base4 + i < tot4) d4[i] = s4[base4 + i];
    }
    __syncthreads();
    const int lane = tid & 31;
    const int c0 = lane * 4;
    const int r0 = (tid >> 5) * 4;
    float acc[4][4] = {};
    for (int k = 0; k < 128; ++k) {
        float4 w = *(const float4*)(W1 + k * 128 + c0);
#pragma unroll
        for (int r = 0; r < 4; ++r) {
            float x = xs[(r0 + r) * 128 + k];
            acc[r][0] = fmaf(x, w.x, acc[r][0]);
            acc[r][1] = fmaf(x, w.y, acc[r][1]);
            acc[r][2] = fmaf(x, w.z, acc[r][2]);
            acc[r][3] = fmaf(x, w.w, acc[r][3]);
        }
    }
    float4 alv = *(const float4*)(al1 + c0);
    float4 arv = *(const float4*)(ar1 + c0);
#pragma unroll
    for (int r = 0; r < 4; ++r) {
        int row = row0 + r0 + r;
        if (row < N) {
            ushort4 fb;
            fb.x = f2bf(acc[r][0]);
            fb.y = f2bf(acc[r][1]);
            fb.z = f2bf(acc[r][2]);
            fb.w = f2bf(acc[r][3]);
            *(ushort4*)(feat1b + (size_t)row * 128 + c0) = fb;
            float pl = acc[r][0] * alv.x + acc[r][1] * alv.y + acc[r][2] * alv.z +
                       acc[r][3] * alv.w;
            float pr = acc[r][0] * arv.x + acc[r][1] * arv.y + acc[r][2] * arv.z +
                       acc[r][3] * arv.w;
#pragma unroll
            for (int off = 4; off >= 1; off >>= 1) {
                pl += __shfl_xor(pl, off, 32);
                pr += __shfl_xor(pr, off, 32);
            }
            if ((lane & 7) == 0) {
                el1[row * 4 + (lane >> 3)] = pl;
                er1[row * 4 + (lane >> 3)] = pr;
            }
        }
    }
}

// ===========================================================================
// GEMM2 fused: feat2b(bf16) = relu(out1) @ W2; el2/er2 fused.
// ===========================================================================
__global__ __launch_bounds__(256) void gemm2_fused(const float* __restrict__ out1,
                                                   const float* __restrict__ W2,
                                                   const float* __restrict__ al2,
                                                   const float* __restrict__ ar2,
                                                   unsigned short* __restrict__ feat2b,
                                                   float* __restrict__ el2,
                                                   float* __restrict__ er2, int N) {
    __shared__ float xs[64 * 128];
    const int tid = threadIdx.x;
    const int row0 = blockIdx.x * 64;
    {
        const float4* s4 = (const float4*)out1;
        float4* d4 = (float4*)xs;
        int base4 = row0 * 32;
        int tot4 = N * 32;
        for (int i = tid; i < 2048; i += 256)
            if (base4 + i < tot4) {
                float4 v = s4[base4 + i];
                v.x = v.x > 0.f ? v.x : 0.f;
                v.y = v.y > 0.f ? v.y : 0.f;
                v.z = v.z > 0.f ? v.z : 0.f;
                v.w = v.w > 0.f ? v.w : 0.f;
                d4[i] = v;
            }
    }
    __syncthreads();
    const int lane = tid & 15;
    const int c0 = lane * 4;
    const int r0 = (tid >> 4) * 4;
    float acc[4][4] = {};
    for (int k = 0; k < 128; ++k) {
        float4 w = *(const float4*)(W2 + k * 64 + c0);
#pragma unroll
        for (int r = 0; r < 4; ++r) {
            float x = xs[(r0 + r) * 128 + k];
            acc[r][0] = fmaf(x, w.x, acc[r][0]);
            acc[r][1] = fmaf(x, w.y, acc[r][1]);
            acc[r][2] = fmaf(x, w.z, acc[r][2]);
            acc[r][3] = fmaf(x, w.w, acc[r][3]);
        }
    }
    float4 alv = *(const float4*)(al2 + c0);
    float4 arv = *(const float4*)(ar2 + c0);
#pragma unroll
    for (int r = 0; r < 4; ++r) {
        int row = row0 + r0 + r;
        if (row < N) {
            ushort4 fb;
            fb.x = f2bf(acc[r][0]);
            fb.y = f2bf(acc[r][1]);
            fb.z = f2bf(acc[r][2]);
            fb.w = f2bf(acc[r][3]);
            *(ushort4*)(feat2b + (size_t)row * 64 + c0) = fb;
            float pl = acc[r][0] * alv.x + acc[r][1] * alv.y + acc[r][2] * alv.z +
                       acc[r][3] * alv.w;
            float pr = acc[r][0] * arv.x + acc[r][1] * arv.y + acc[r][2] * arv.z +
                       acc[r][3] * arv.w;
#pragma unroll
            for (int off = 8; off >= 1; off >>= 1) {
                pl += __shfl_xor(pl, off, 16);
                pr += __shfl_xor(pr, off, 16);
            }
            if (lane == 0) {
                el2[row] = pl;
                er2[row] = pr;
            }
        }
    }
}

// ===========================================================================
// Gather layer 1: one wave per dst; LDS-staged 64-edge batches.
// ===========================================================================
__global__ __launch_bounds__(64) void gather1_kernel(const int* __restrict__ row_start,
                                                     const int* __restrict__ srcs,
                                                     const float* __restrict__ el1,
                                                     const float* __restrict__ er1,
                                                     const unsigned short* __restrict__ feat1b,
                                                     const float* __restrict__ b1,
                                                     float* __restrict__ out1) {
    const int d = blockIdx.x;
    const int tid = threadIdx.x;  // 0..63
    const int beg = row_start[d], end = row_start[d + 1];
    const int h = tid >> 4;
    const int c = tid * 2;
    __shared__ int s_sh[64];
    __shared__ float a_sh[256];
    float4 er4 = *(const float4*)(er1 + (size_t)d * 4);
    float acc0 = 0.f, acc1 = 0.f, bcc0 = 0.f, bcc1 = 0.f, den = 0.f;
    for (int k0 = beg; k0 < end; k0 += 64) {
        const int M = min(64, end - k0);
        if (tid < M) {
            int s = srcs[k0 + tid];
            s_sh[tid] = s;
            float4 el4 = *(const float4*)(el1 + (size_t)s * 4);
            float v0 = el4.x + er4.x;
            float v1 = el4.y + er4.y;
            float v2 = el4.z + er4.z;
            float v3 = el4.w + er4.w;
            v0 = v0 > 0.f ? v0 : NEG_SLOPE * v0;
            v1 = v1 > 0.f ? v1 : NEG_SLOPE * v1;
            v2 = v2 > 0.f ? v2 : NEG_SLOPE * v2;
            v3 = v3 > 0.f ? v3 : NEG_SLOPE * v3;
            a_sh[tid * 4 + 0] = __expf(v0);
            a_sh[tid * 4 + 1] = __expf(v1);
            a_sh[tid * 4 + 2] = __expf(v2);
            a_sh[tid * 4 + 3] = __expf(v3);
        }
        __syncthreads();
        int m = 0;
        for (; m + 1 < M; m += 2) {
            int s0 = s_sh[m], s1 = s_sh[m + 1];
            float a0 = a_sh[m * 4 + h];
            float a1 = a_sh[(m + 1) * 4 + h];
            ushort2 f0 = *(const ushort2*)(feat1b + (size_t)s0 * 128 + c);
            ushort2 f1 = *(const ushort2*)(feat1b + (size_t)s1 * 128 + c);
            den += a0 + a1;
            acc0 = fmaf(bf2f(f0.x), a0, acc0);
            acc1 = fmaf(bf2f(f0.y), a0, acc1);
            bcc0 = fmaf(bf2f(f1.x), a1, bcc0);
            bcc1 = fmaf(bf2f(f1.y), a1, bcc1);
        }
        if (m < M) {
            int s0 = s_sh[m];
            float a0 = a_sh[m * 4 + h];
            ushort2 f0 = *(const ushort2*)(feat1b + (size_t)s0 * 128 + c);
            den += a0;
            acc0 = fmaf(bf2f(f0.x), a0, acc0);
            acc1 = fmaf(bf2f(f0.y), a0, acc1);
        }
        __syncthreads();
    }
    acc0 += bcc0;
    acc1 += bcc1;
    float inv = (end > beg) ? 1.f / den : 0.f;
    *(float2*)(out1 + (size_t)d * 128 + c) =
        make_float2(acc0 * inv + b1[c], acc1 * inv + b1[c + 1]);
}

// ===========================================================================
// Gather layer 2: one wave per dst; LDS-staged 64-edge batches. H=1, D=64.
// ===========================================================================
__global__ __launch_bounds__(64) void gather2_kernel(const int* __restrict__ row_start,
                                                     const int* __restrict__ srcs,
                                                     const float* __restrict__ el2,
                                                     const float* __restrict__ er2,
                                                     const unsigned short* __restrict__ feat2b,
                                                     const float* __restrict__ b2,
                                                     float* __restrict__ out2) {
    const int d = blockIdx.x;
    const int tid = threadIdx.x;  // 0..63
    const int beg = row_start[d], end = row_start[d + 1];
    const float er_d = er2[d];
    __shared__ int s_sh[64];
    __shared__ float a_sh[64];
    float acc0 = 0.f, acc1 = 0.f, den = 0.f;
    for (int k0 = beg; k0 < end; k0 += 64) {
        const int M = min(64, end - k0);
        if (tid < M) {
            int s = srcs[k0 + tid];
            s_sh[tid] = s;
            float v = el2[s] + er_d;
            v = v > 0.f ? v : NEG_SLOPE * v;
            a_sh[tid] = __expf(v);
        }
        __syncthreads();
        int m = 0;
        for (; m + 1 < M; m += 2) {
            int s0 = s_sh[m], s1 = s_sh[m + 1];
            float a0 = a_sh[m], a1 = a_sh[m + 1];
            float f0 = bf2f(feat2b[(size_t)s0 * 64 + tid]);
            float f1 = bf2f(feat2b[(size_t)s1 * 64 + tid]);
            den += a0 + a1;
            acc0 = fmaf(f0, a0, acc0);
            acc1 = fmaf(f1, a1, acc1);
        }
        if (m < M) {
            int s0 = s_sh[m];
            float a0 = a_sh[m];
            den += a0;
            acc0 = fmaf(bf2f(feat2b[(size_t)s0 * 64 + tid]), a0, acc0);
        }
        __syncthreads();
    }
    acc0 += acc1;
    float inv = (end > beg) ? 1.f / den : 0.f;
    out2[(size_t)d * 64 + tid] = acc0 * inv + b2[tid];
}

// ===========================================================================
extern "C" void kernel_launch(void* const* d_in, const int* in_sizes, int n_in,
                              void* d_out, int out_size, void* d_ws, size_t ws_size,
                              hipStream_t stream) {
    const float* h   = (const float*)d_in[0];
    const int*   src = (const int*)d_in[1];
    const int*   dst = (const int*)d_in[2];
    const float* W1  = (const float*)d_in[3];
    const float* al1 = (const float*)d_in[4];
    const float* ar1 = (const float*)d_in[5];
    const float* b1  = (const float*)d_in[6];
    const float* W2  = (const float*)d_in[7];
    const float* al2 = (const float*)d_in[8];
    const float* ar2 = (const float*)d_in[9];
    const float* b2  = (const float*)d_in[10];

    const int N = in_sizes[0] / 128;  // 50000 (pack assumes N <= 65536)
    const int E = in_sizes[1];        // 800000
    const int NB = (N + 63) >> 6;     // 782 buckets

    char* ws = (char*)d_ws;
    size_t off = 0;
    auto alloc = [&](size_t elems) -> void* {  // elems are 4-byte units
        void* p = (void*)(ws + off);
        off += ((elems * 4 + 255) / 256) * 256;
        return p;
    };
    int* bucket_cnt    = (int*)alloc(NB);
    int* bucket_base   = (int*)alloc(NB + 1);
    int* bucket_cursor = (int*)alloc(NB);
    unsigned* tmp      = (unsigned*)alloc(E);
    int* srcs          = (int*)alloc(E);
    int* row_start     = (int*)alloc(N + 1);
    float* el1   = (float*)alloc((size_t)N * 4);
    float* er1   = (float*)alloc((size_t)N * 4);
    unsigned short* feat1b = (unsigned short*)alloc((size_t)N * 64);  // N*128 bf16
    float* out1  = (float*)alloc((size_t)N * 128);
    float* el2   = (float*)alloc(N);
    float* er2   = (float*)alloc(N);
    unsigned short* feat2b = (unsigned short*)alloc((size_t)N * 32);  // N*64 bf16
    float* out2  = (float*)d_out;

    const int nchunks = (E + CH - 1) / CH;

    // --- CSR build (write-combined radix partition) ---
    zerob_kernel<<<(NB + 255) / 256, 256, 0, stream>>>(bucket_cnt, NB);
    bucketA_kernel<<<nchunks, 256, 0, stream>>>(dst, bucket_cnt, E, NB);
    bucketB_kernel<<<1, 1024, 0, stream>>>(bucket_cnt, bucket_base, bucket_cursor,
                                           row_start, N, NB, E);
    bucketC_kernel<<<nchunks, 256, 0, stream>>>(src, dst, bucket_cursor, tmp, E, NB);
    bucketD_kernel<<<NB, 64, 0, stream>>>(tmp, bucket_base, srcs, row_start, N, NB);

    // --- layer 1 ---
    gemm1_fused<<<(N + 31) / 32, 256, 0, stream>>>(h, W1, al1, ar1, feat1b, el1, er1, N);
    gather1_kernel<<<N, 64, 0, stream>>>(row_start, srcs, el1, er1, feat1b, b1, out1);

    // --- layer 2 ---
    gemm2_fused<<<(N + 63) / 64, 256, 0, stream>>>(out1, W2, al2, ar2, feat2b, el2, er2, N);
    gather2_kernel<<<N, 64, 0, stream>>>(row_start, srcs, el2, er2, feat2b, b2, out2);
}

// Round 6
// 254.042 us; speedup vs baseline: 3.8613x; 1.0024x over previous
//
#include <hip/hip_runtime.h>

#define NEG_SLOPE 0.2f
#define CH 4096      // edges per partition block
#define DCAP 2048    // max edges per bucket handled via LDS fast path

__device__ inline unsigned short f2bf(float f) {
    unsigned u = __float_as_uint(f);
    unsigned r = (u + 0x7FFFu + ((u >> 16) & 1u)) >> 16;
    return (unsigned short)r;
}
__device__ inline float bf2f(unsigned short s) {
    return __uint_as_float(((unsigned)s) << 16);
}

// ===========================================================================
// CSR build via write-combined radix partition. bucket = dst>>6 (64 dsts each).
// Packed edge: (bucket<<22) | ((dst&63)<<16) | src   (requires N <= 65536)
// ===========================================================================
__global__ void zerob_kernel(int* __restrict__ p, int n) {
    int i = blockIdx.x * blockDim.x + threadIdx.x;
    if (i < n) p[i] = 0;
}

__global__ __launch_bounds__(256) void bucketA_kernel(const int* __restrict__ dst,
                                                      int* __restrict__ bucket_cnt,
                                                      int E, int NB) {
    __shared__ int lh[1024];
    const int tid = threadIdx.x;
    for (int i = tid; i < 1024; i += 256) lh[i] = 0;
    __syncthreads();
    const int base = blockIdx.x * CH;
    const int cnt = min(CH, E - base);
    for (int i = tid; i < cnt; i += 256) atomicAdd(&lh[dst[base + i] >> 6], 1);
    __syncthreads();
    for (int b = tid; b < NB; b += 256)
        if (lh[b]) atomicAdd(&bucket_cnt[b], lh[b]);
}

__global__ __launch_bounds__(1024) void bucketB_kernel(const int* __restrict__ bucket_cnt,
                                                       int* __restrict__ bucket_base,
                                                       int* __restrict__ bucket_cursor,
                                                       int* __restrict__ row_start,
                                                       int N, int NB, int E) {
    __shared__ int sh[1024];
    const int tid = threadIdx.x;
    int v = (tid < NB) ? bucket_cnt[tid] : 0;
    sh[tid] = v;
    __syncthreads();
    for (int off = 1; off < 1024; off <<= 1) {
        int t = (tid >= off) ? sh[tid - off] : 0;
        __syncthreads();
        sh[tid] += t;
        __syncthreads();
    }
    int ex = sh[tid] - v;
    if (tid < NB) {
        bucket_base[tid] = ex;
        bucket_cursor[tid] = ex;
    }
    if (tid == NB - 1) bucket_base[NB] = ex + v;  // == E
    if (tid == 0) row_start[N] = E;
}

__global__ __launch_bounds__(256) void bucketC_kernel(const int* __restrict__ src,
                                                      const int* __restrict__ dst,
                                                      int* __restrict__ bucket_cursor,
                                                      unsigned* __restrict__ tmp,
                                                      int E, int NB) {
    __shared__ int lh[1024];        // per-bucket counts (padded to 1024)
    __shared__ int lex[1024];       // per-bucket exclusive prefix
    __shared__ int lcur[1024];      // per-bucket placement cursor
    __shared__ int gbase_sh[1024];  // per-bucket global base for this block
    __shared__ int psum[256];
    __shared__ unsigned sortedv[CH];
    const int tid = threadIdx.x;
    const int base_e = blockIdx.x * CH;
    const int cnt_e = min(CH, E - base_e);
    for (int i = tid; i < 1024; i += 256) lh[i] = 0;
    __syncthreads();
    for (int i = tid; i < cnt_e; i += 256) atomicAdd(&lh[dst[base_e + i] >> 6], 1);
    __syncthreads();
    int s0 = lh[tid * 4], s1 = lh[tid * 4 + 1], s2 = lh[tid * 4 + 2], s3 = lh[tid * 4 + 3];
    int tot = s0 + s1 + s2 + s3;
    psum[tid] = tot;
    __syncthreads();
    for (int off = 1; off < 256; off <<= 1) {
        int t = (tid >= off) ? psum[tid - off] : 0;
        __syncthreads();
        psum[tid] += t;
        __syncthreads();
    }
    int ebase = psum[tid] - tot;
    lex[tid * 4] = ebase;
    lex[tid * 4 + 1] = ebase + s0;
    lex[tid * 4 + 2] = ebase + s0 + s1;
    lex[tid * 4 + 3] = ebase + s0 + s1 + s2;
    __syncthreads();
    for (int b = tid; b < NB; b += 256) {
        int c = lh[b];
        gbase_sh[b] = c ? atomicAdd(&bucket_cursor[b], c) : 0;
        lcur[b] = 0;
    }
    __syncthreads();
    for (int i = tid; i < cnt_e; i += 256) {
        int e = base_e + i;
        int d = dst[e];
        unsigned b = (unsigned)d >> 6;
        int r = atomicAdd(&lcur[b], 1);
        sortedv[lex[b] + r] = (b << 22) | ((unsigned)(d & 63) << 16) | (unsigned)(src[e] & 0xFFFF);
    }
    __syncthreads();
    for (int i = tid; i < cnt_e; i += 256) {
        unsigned v = sortedv[i];
        int b = v >> 22;
        tmp[gbase_sh[b] + (i - lex[b])] = v;
    }
}

__global__ __launch_bounds__(64) void bucketD_kernel(const unsigned* __restrict__ tmp,
                                                     const int* __restrict__ bucket_base,
                                                     int* __restrict__ srcs,
                                                     int* __restrict__ row_start,
                                                     int N, int NB) {
    __shared__ unsigned sval[DCAP];
    __shared__ int ssrc[DCAP];
    __shared__ int dh[64], dex[64], dcur[64];
    const int b = blockIdx.x;
    const int tid = threadIdx.x;  // one wave
    const int gb = bucket_base[b], ge = bucket_base[b + 1];
    const int cnt = ge - gb;
    dh[tid] = 0;
    __syncthreads();
    if (cnt <= DCAP) {
        for (int i = tid; i < cnt; i += 64) {
            unsigned v = tmp[gb + i];
            sval[i] = v;
            atomicAdd(&dh[(v >> 16) & 63], 1);
        }
        __syncthreads();
        int v = dh[tid], inc = v;
        for (int off = 1; off < 64; off <<= 1) {
            int t = __shfl_up(inc, off, 64);
            if (tid >= off) inc += t;
        }
        int ex = inc - v;
        dex[tid] = ex;
        dcur[tid] = 0;
        __syncthreads();
        for (int i = tid; i < cnt; i += 64) {
            unsigned val = sval[i];
            int dl = (val >> 16) & 63;
            int r = atomicAdd(&dcur[dl], 1);
            ssrc[dex[dl] + r] = (int)(val & 0xFFFFu);
        }
        __syncthreads();
        for (int i = tid; i < cnt; i += 64) srcs[gb + i] = ssrc[i];
        int dglob = b * 64 + tid;
        if (dglob < N) row_start[dglob] = gb + ex;
    } else {
        for (int i = tid; i < cnt; i += 64) atomicAdd(&dh[(tmp[gb + i] >> 16) & 63], 1);
        __syncthreads();
        int v = dh[tid], inc = v;
        for (int off = 1; off < 64; off <<= 1) {
            int t = __shfl_up(inc, off, 64);
            if (tid >= off) inc += t;
        }
        int ex = inc - v;
        dex[tid] = ex;
        dcur[tid] = 0;
        __syncthreads();
        for (int i = tid; i < cnt; i += 64) {
            unsigned val = tmp[gb + i];
            int dl = (val >> 16) & 63;
            int r = atomicAdd(&dcur[dl], 1);
            srcs[gb + dex[dl] + r] = (int)(val & 0xFFFFu);
        }
        int dglob = b * 64 + tid;
        if (dglob < N) row_start[dglob] = gb + ex;
    }
}

// ===========================================================================
// GEMM1 fused: feat1b(bf16) = h @ W1; el1/er1 from fp32 accumulators.
// 64 rows/block, 256 threads, 8x4 per thread (32 FMA per W float4).
// ===========================================================================
__global__ __launch_bounds__(256) void gemm1_fused(const float* __restrict__ h,
                                                   const float* __restrict__ W1,
                                                   const float* __restrict__ al1,
                                                   const float* __restrict__ ar1,
                                                   unsigned short* __restrict__ feat1b,
                                                   float* __restrict__ el1,
                                                   float* __restrict__ er1, int N) {
    __shared__ float xs[64 * 128];
    const int tid = threadIdx.x;
    const int row0 = blockIdx.x * 64;
    {
        const float4* s4 = (const float4*)h;
        float4* d4 = (float4*)xs;
        int base4 = row0 * 32;
        int tot4 = N * 32;
        for (int i = tid; i < 2048; i += 256)
            if (base4 + i < tot4) d4[i] = s4[base4 + i];
    }
    __syncthreads();
    const int lane = tid & 31;
    const int c0 = lane * 4;
    const int r0 = (tid >> 5) * 8;  // 8 groups x 8 rows = 64
    float acc[8][4] = {};
#pragma unroll 4
    for (int k = 0; k < 128; ++k) {
        float4 w = *(const float4*)(W1 + k * 128 + c0);
#pragma unroll
        for (int r = 0; r < 8; ++r) {
            float x = xs[(r0 + r) * 128 + k];
            acc[r][0] = fmaf(x, w.x, acc[r][0]);
            acc[r][1] = fmaf(x, w.y, acc[r][1]);
            acc[r][2] = fmaf(x, w.z, acc[r][2]);
            acc[r][3] = fmaf(x, w.w, acc[r][3]);
        }
    }
    float4 alv = *(const float4*)(al1 + c0);
    float4 arv = *(const float4*)(ar1 + c0);
#pragma unroll
    for (int r = 0; r < 8; ++r) {
        int row = row0 + r0 + r;
        if (row < N) {
            ushort4 fb;
            fb.x = f2bf(acc[r][0]);
            fb.y = f2bf(acc[r][1]);
            fb.z = f2bf(acc[r][2]);
            fb.w = f2bf(acc[r][3]);
            *(ushort4*)(feat1b + (size_t)row * 128 + c0) = fb;
            float pl = acc[r][0] * alv.x + acc[r][1] * alv.y + acc[r][2] * alv.z +
                       acc[r][3] * alv.w;
            float pr = acc[r][0] * arv.x + acc[r][1] * arv.y + acc[r][2] * arv.z +
                       acc[r][3] * arv.w;
#pragma unroll
            for (int off = 4; off >= 1; off >>= 1) {
                pl += __shfl_xor(pl, off, 32);
                pr += __shfl_xor(pr, off, 32);
            }
            if ((lane & 7) == 0) {
                el1[row * 4 + (lane >> 3)] = pl;
                er1[row * 4 + (lane >> 3)] = pr;
            }
        }
    }
}

// ===========================================================================
// GEMM2 fused: feat2b(bf16) = relu(out1) @ W2; el2/er2 fused.
// 128 rows/block, 256 threads, 8x4 per thread.
// ===========================================================================
__global__ __launch_bounds__(256) void gemm2_fused(const float* __restrict__ out1,
                                                   const float* __restrict__ W2,
                                                   const float* __restrict__ al2,
                                                   const float* __restrict__ ar2,
                                                   unsigned short* __restrict__ feat2b,
                                                   float* __restrict__ el2,
                                                   float* __restrict__ er2, int N) {
    __shared__ float xs[128 * 128];  // 64 KB
    const int tid = threadIdx.x;
    const int row0 = blockIdx.x * 128;
    {
        const float4* s4 = (const float4*)out1;
        float4* d4 = (float4*)xs;
        int base4 = row0 * 32;
        int tot4 = N * 32;
        for (int i = tid; i < 4096; i += 256)
            if (base4 + i < tot4) {
                float4 v = s4[base4 + i];
                v.x = v.x > 0.f ? v.x : 0.f;
                v.y = v.y > 0.f ? v.y : 0.f;
                v.z = v.z > 0.f ? v.z : 0.f;
                v.w = v.w > 0.f ? v.w : 0.f;
                d4[i] = v;
            }
    }
    __syncthreads();
    const int lane = tid & 15;
    const int c0 = lane * 4;
    const int r0 = (tid >> 4) * 8;  // 16 groups x 8 rows = 128
    float acc[8][4] = {};
#pragma unroll 4
    for (int k = 0; k < 128; ++k) {
        float4 w = *(const float4*)(W2 + k * 64 + c0);
#pragma unroll
        for (int r = 0; r < 8; ++r) {
            float x = xs[(r0 + r) * 128 + k];
            acc[r][0] = fmaf(x, w.x, acc[r][0]);
            acc[r][1] = fmaf(x, w.y, acc[r][1]);
            acc[r][2] = fmaf(x, w.z, acc[r][2]);
            acc[r][3] = fmaf(x, w.w, acc[r][3]);
        }
    }
    float4 alv = *(const float4*)(al2 + c0);
    float4 arv = *(const float4*)(ar2 + c0);
#pragma unroll
    for (int r = 0; r < 8; ++r) {
        int row = row0 + r0 + r;
        if (row < N) {
            ushort4 fb;
            fb.x = f2bf(acc[r][0]);
            fb.y = f2bf(acc[r][1]);
            fb.z = f2bf(acc[r][2]);
            fb.w = f2bf(acc[r][3]);
            *(ushort4*)(feat2b + (size_t)row * 64 + c0) = fb;
            float pl = acc[r][0] * alv.x + acc[r][1] * alv.y + acc[r][2] * alv.z +
                       acc[r][3] * alv.w;
            float pr = acc[r][0] * arv.x + acc[r][1] * arv.y + acc[r][2] * arv.z +
                       acc[r][3] * arv.w;
#pragma unroll
            for (int off = 8; off >= 1; off >>= 1) {
                pl += __shfl_xor(pl, off, 16);
                pr += __shfl_xor(pr, off, 16);
            }
            if (lane == 0) {
                el2[row] = pl;
                er2[row] = pr;
            }
        }
    }
}

// ===========================================================================
// Gather layer 1: one wave per dst; LDS-staged 64-edge batches.
// ===========================================================================
__global__ __launch_bounds__(64) void gather1_kernel(const int* __restrict__ row_start,
                                                     const int* __restrict__ srcs,
                                                     const float* __restrict__ el1,
                                                     const float* __restrict__ er1,
                                                     const unsigned short* __restrict__ feat1b,
                                                     const float* __restrict__ b1,
                                                     float* __restrict__ out1) {
    const int d = blockIdx.x;
    const int tid = threadIdx.x;  // 0..63
    const int beg = row_start[d], end = row_start[d + 1];
    const int h = tid >> 4;
    const int c = tid * 2;
    __shared__ int s_sh[64];
    __shared__ float a_sh[256];
    float4 er4 = *(const float4*)(er1 + (size_t)d * 4);
    float acc0 = 0.f, acc1 = 0.f, bcc0 = 0.f, bcc1 = 0.f, den = 0.f;
    for (int k0 = beg; k0 < end; k0 += 64) {
        const int M = min(64, end - k0);
        if (tid < M) {
            int s = srcs[k0 + tid];
            s_sh[tid] = s;
            float4 el4 = *(const float4*)(el1 + (size_t)s * 4);
            float v0 = el4.x + er4.x;
            float v1 = el4.y + er4.y;
            float v2 = el4.z + er4.z;
            float v3 = el4.w + er4.w;
            v0 = v0 > 0.f ? v0 : NEG_SLOPE * v0;
            v1 = v1 > 0.f ? v1 : NEG_SLOPE * v1;
            v2 = v2 > 0.f ? v2 : NEG_SLOPE * v2;
            v3 = v3 > 0.f ? v3 : NEG_SLOPE * v3;
            a_sh[tid * 4 + 0] = __expf(v0);
            a_sh[tid * 4 + 1] = __expf(v1);
            a_sh[tid * 4 + 2] = __expf(v2);
            a_sh[tid * 4 + 3] = __expf(v3);
        }
        __syncthreads();
        int m = 0;
        for (; m + 1 < M; m += 2) {
            int s0 = s_sh[m], s1 = s_sh[m + 1];
            float a0 = a_sh[m * 4 + h];
            float a1 = a_sh[(m + 1) * 4 + h];
            ushort2 f0 = *(const ushort2*)(feat1b + (size_t)s0 * 128 + c);
            ushort2 f1 = *(const ushort2*)(feat1b + (size_t)s1 * 128 + c);
            den += a0 + a1;
            acc0 = fmaf(bf2f(f0.x), a0, acc0);
            acc1 = fmaf(bf2f(f0.y), a0, acc1);
            bcc0 = fmaf(bf2f(f1.x), a1, bcc0);
            bcc1 = fmaf(bf2f(f1.y), a1, bcc1);
        }
        if (m < M) {
            int s0 = s_sh[m];
            float a0 = a_sh[m * 4 + h];
            ushort2 f0 = *(const ushort2*)(feat1b + (size_t)s0 * 128 + c);
            den += a0;
            acc0 = fmaf(bf2f(f0.x), a0, acc0);
            acc1 = fmaf(bf2f(f0.y), a0, acc1);
        }
        __syncthreads();
    }
    acc0 += bcc0;
    acc1 += bcc1;
    float inv = (end > beg) ? 1.f / den : 0.f;
    *(float2*)(out1 + (size_t)d * 128 + c) =
        make_float2(acc0 * inv + b1[c], acc1 * inv + b1[c + 1]);
}

// ===========================================================================
// Gather layer 2: one wave per dst; LDS-staged 64-edge batches. H=1, D=64.
// ===========================================================================
__global__ __launch_bounds__(64) void gather2_kernel(const int* __restrict__ row_start,
                                                     const int* __restrict__ srcs,
                                                     const float* __restrict__ el2,
                                                     const float* __restrict__ er2,
                                                     const unsigned short* __restrict__ feat2b,
                                                     const float* __restrict__ b2,
                                                     float* __restrict__ out2) {
    const int d = blockIdx.x;
    const int tid = threadIdx.x;  // 0..63
    const int beg = row_start[d], end = row_start[d + 1];
    const float er_d = er2[d];
    __shared__ int s_sh[64];
    __shared__ float a_sh[64];
    float acc0 = 0.f, acc1 = 0.f, den = 0.f;
    for (int k0 = beg; k0 < end; k0 += 64) {
        const int M = min(64, end - k0);
        if (tid < M) {
            int s = srcs[k0 + tid];
            s_sh[tid] = s;
            float v = el2[s] + er_d;
            v = v > 0.f ? v : NEG_SLOPE * v;
            a_sh[tid] = __expf(v);
        }
        __syncthreads();
        int m = 0;
        for (; m + 1 < M; m += 2) {
            int s0 = s_sh[m], s1 = s_sh[m + 1];
            float a0 = a_sh[m], a1 = a_sh[m + 1];
            float f0 = bf2f(feat2b[(size_t)s0 * 64 + tid]);
            float f1 = bf2f(feat2b[(size_t)s1 * 64 + tid]);
            den += a0 + a1;
            acc0 = fmaf(f0, a0, acc0);
            acc1 = fmaf(f1, a1, acc1);
        }
        if (m < M) {
            int s0 = s_sh[m];
            float a0 = a_sh[m];
            den += a0;
            acc0 = fmaf(bf2f(feat2b[(size_t)s0 * 64 + tid]), a0, acc0);
        }
        __syncthreads();
    }
    acc0 += acc1;
    float inv = (end > beg) ? 1.f / den : 0.f;
    out2[(size_t)d * 64 + tid] = acc0 * inv + b2[tid];
}

// ===========================================================================
extern "C" void kernel_launch(void* const* d_in, const int* in_sizes, int n_in,
                              void* d_out, int out_size, void* d_ws, size_t ws_size,
                              hipStream_t stream) {
    const float* h   = (const float*)d_in[0];
    const int*   src = (const int*)d_in[1];
    const int*   dst = (const int*)d_in[2];
    const float* W1  = (const float*)d_in[3];
    const float* al1 = (const float*)d_in[4];
    const float* ar1 = (const float*)d_in[5];
    const float* b1  = (const float*)d_in[6];
    const float* W2  = (const float*)d_in[7];
    const float* al2 = (const float*)d_in[8];
    const float* ar2 = (const float*)d_in[9];
    const float* b2  = (const float*)d_in[10];

    const int N = in_sizes[0] / 128;  // 50000 (pack assumes N <= 65536)
    const int E = in_sizes[1];        // 800000
    const int NB = (N + 63) >> 6;     // 782 buckets

    char* ws = (char*)d_ws;
    size_t off = 0;
    auto alloc = [&](size_t elems) -> void* {  // elems are 4-byte units
        void* p = (void*)(ws + off);
        off += ((elems * 4 + 255) / 256) * 256;
        return p;
    };
    int* bucket_cnt    = (int*)alloc(NB);
    int* bucket_base   = (int*)alloc(NB + 1);
    int* bucket_cursor = (int*)alloc(NB);
    unsigned* tmp      = (unsigned*)alloc(E);
    int* srcs          = (int*)alloc(E);
    int* row_start     = (int*)alloc(N + 1);
    float* el1   = (float*)alloc((size_t)N * 4);
    float* er1   = (float*)alloc((size_t)N * 4);
    unsigned short* feat1b = (unsigned short*)alloc((size_t)N * 64);  // N*128 bf16
    float* out1  = (float*)alloc((size_t)N * 128);
    float* el2   = (float*)alloc(N);
    float* er2   = (float*)alloc(N);
    unsigned short* feat2b = (unsigned short*)alloc((size_t)N * 32);  // N*64 bf16
    float* out2  = (float*)d_out;

    const int nchunks = (E + CH - 1) / CH;

    // --- CSR build (write-combined radix partition) ---
    zerob_kernel<<<(NB + 255) / 256, 256, 0, stream>>>(bucket_cnt, NB);
    bucketA_kernel<<<nchunks, 256, 0, stream>>>(dst, bucket_cnt, E, NB);
    bucketB_kernel<<<1, 1024, 0, stream>>>(bucket_cnt, bucket_base, bucket_cursor,
                                           row_start, N, NB, E);
    bucketC_kernel<<<nchunks, 256, 0, stream>>>(src, dst, bucket_cursor, tmp, E, NB);
    bucketD_kernel<<<NB, 64, 0, stream>>>(tmp, bucket_base, srcs, row_start, N, NB);

    // --- layer 1 ---
    gemm1_fused<<<(N + 63) / 64, 256, 0, stream>>>(h, W1, al1, ar1, feat1b, el1, er1, N);
    gather1_kernel<<<N, 64, 0, stream>>>(row_start, srcs, el1, er1, feat1b, b1, out1);

    // --- layer 2 ---
    gemm2_fused<<<(N + 127) / 128, 256, 0, stream>>>(out1, W2, al2, ar2, feat2b, el2, er2, N);
    gather2_kernel<<<N, 64, 0, stream>>>(row_start, srcs, el2, er2, feat2b, b2, out2);
}

// Round 7
// 231.884 us; speedup vs baseline: 4.2303x; 1.0956x over previous
//
#include <hip/hip_runtime.h>

#define NEG_SLOPE 0.2f
#define CH 4096      // edges per partition block
#define DCAP 2048    // max edges per bucket handled via LDS fast path

__device__ inline unsigned short f2bf(float f) {
    unsigned u = __float_as_uint(f);
    unsigned r = (u + 0x7FFFu + ((u >> 16) & 1u)) >> 16;
    return (unsigned short)r;
}
__device__ inline float bf2f(unsigned short s) {
    return __uint_as_float(((unsigned)s) << 16);
}
__device__ inline void wave_lds_fence() {
    // LDS ops from one wave are processed in order by the DS unit; this makes
    // the write->read visible ordering explicit and stops compiler reordering.
    asm volatile("s_waitcnt lgkmcnt(0)" ::: "memory");
}

// ===========================================================================
// CSR build via write-combined radix partition. bucket = dst>>6 (64 dsts each).
// Packed edge: (bucket<<22) | ((dst&63)<<16) | src   (requires N <= 65536)
// ===========================================================================
__global__ void zerob_kernel(int* __restrict__ p, int n) {
    int i = blockIdx.x * blockDim.x + threadIdx.x;
    if (i < n) p[i] = 0;
}

__global__ __launch_bounds__(256) void bucketA_kernel(const int* __restrict__ dst,
                                                      int* __restrict__ bucket_cnt,
                                                      int E, int NB) {
    __shared__ int lh[1024];
    const int tid = threadIdx.x;
    for (int i = tid; i < 1024; i += 256) lh[i] = 0;
    __syncthreads();
    const int base = blockIdx.x * CH;
    const int cnt = min(CH, E - base);
    for (int i = tid; i < cnt; i += 256) atomicAdd(&lh[dst[base + i] >> 6], 1);
    __syncthreads();
    for (int b = tid; b < NB; b += 256)
        if (lh[b]) atomicAdd(&bucket_cnt[b], lh[b]);
}

__global__ __launch_bounds__(1024) void bucketB_kernel(const int* __restrict__ bucket_cnt,
                                                       int* __restrict__ bucket_base,
                                                       int* __restrict__ bucket_cursor,
                                                       int* __restrict__ row_start,
                                                       int N, int NB, int E) {
    __shared__ int sh[1024];
    const int tid = threadIdx.x;
    int v = (tid < NB) ? bucket_cnt[tid] : 0;
    sh[tid] = v;
    __syncthreads();
    for (int off = 1; off < 1024; off <<= 1) {
        int t = (tid >= off) ? sh[tid - off] : 0;
        __syncthreads();
        sh[tid] += t;
        __syncthreads();
    }
    int ex = sh[tid] - v;
    if (tid < NB) {
        bucket_base[tid] = ex;
        bucket_cursor[tid] = ex;
    }
    if (tid == NB - 1) bucket_base[NB] = ex + v;  // == E
    if (tid == 0) row_start[N] = E;
}

// ===========================================================================
// FUSED: bucketC (edge partition) || gemm1 (feat1b = h@W1 + el1/er1).
// blocks [0, nchunks) do partition; blocks [nchunks, ...) do GEMM rows.
// Shared 33 KB LDS union.
// ===========================================================================
__global__ __launch_bounds__(256) void csrC_gemm1_kernel(
    const int* __restrict__ src, const int* __restrict__ dst,
    int* __restrict__ bucket_cursor, unsigned* __restrict__ tmp, int E, int NB,
    int nchunks, const float* __restrict__ h, const float* __restrict__ W1,
    const float* __restrict__ al1, const float* __restrict__ ar1,
    unsigned short* __restrict__ feat1b, float* __restrict__ el1,
    float* __restrict__ er1, int N) {
    __shared__ __align__(16) int smem[8448];  // 33 KB union
    const int tid = threadIdx.x;
    if ((int)blockIdx.x < nchunks) {
        // ---------------- bucketC body ----------------
        int* lh = smem;                               // 1024
        int* lex = smem + 1024;                       // 1024
        int* lcur = smem + 2048;                      // 1024
        int* gbase_sh = smem + 3072;                  // 1024
        int* psum = smem + 4096;                      // 256
        unsigned* sortedv = (unsigned*)(smem + 4352); // 4096
        const int base_e = blockIdx.x * CH;
        const int cnt_e = min(CH, E - base_e);
        for (int i = tid; i < 1024; i += 256) lh[i] = 0;
        __syncthreads();
        for (int i = tid; i < cnt_e; i += 256) atomicAdd(&lh[dst[base_e + i] >> 6], 1);
        __syncthreads();
        int s0 = lh[tid * 4], s1 = lh[tid * 4 + 1], s2 = lh[tid * 4 + 2], s3 = lh[tid * 4 + 3];
        int tot = s0 + s1 + s2 + s3;
        psum[tid] = tot;
        __syncthreads();
        for (int off = 1; off < 256; off <<= 1) {
            int t = (tid >= off) ? psum[tid - off] : 0;
            __syncthreads();
            psum[tid] += t;
            __syncthreads();
        }
        int ebase = psum[tid] - tot;
        lex[tid * 4] = ebase;
        lex[tid * 4 + 1] = ebase + s0;
        lex[tid * 4 + 2] = ebase + s0 + s1;
        lex[tid * 4 + 3] = ebase + s0 + s1 + s2;
        __syncthreads();
        for (int b = tid; b < NB; b += 256) {
            int c = lh[b];
            gbase_sh[b] = c ? atomicAdd(&bucket_cursor[b], c) : 0;
            lcur[b] = 0;
        }
        __syncthreads();
        for (int i = tid; i < cnt_e; i += 256) {
            int e = base_e + i;
            int d = dst[e];
            unsigned b = (unsigned)d >> 6;
            int r = atomicAdd(&lcur[b], 1);
            sortedv[lex[b] + r] =
                (b << 22) | ((unsigned)(d & 63) << 16) | (unsigned)(src[e] & 0xFFFF);
        }
        __syncthreads();
        for (int i = tid; i < cnt_e; i += 256) {
            unsigned v = sortedv[i];
            int b = v >> 22;
            tmp[gbase_sh[b] + (i - lex[b])] = v;
        }
    } else {
        // ---------------- gemm1 body ----------------
        float* xs = (float*)smem;  // 64*128 floats = 32 KB
        const int row0 = ((int)blockIdx.x - nchunks) * 64;
        {
            const float4* s4 = (const float4*)h;
            float4* d4 = (float4*)xs;
            int base4 = row0 * 32;
            int tot4 = N * 32;
            for (int i = tid; i < 2048; i += 256)
                if (base4 + i < tot4) d4[i] = s4[base4 + i];
        }
        __syncthreads();
        const int lane = tid & 31;
        const int c0 = lane * 4;
        const int r0 = (tid >> 5) * 8;
        float acc[8][4] = {};
#pragma unroll 4
        for (int k = 0; k < 128; ++k) {
            float4 w = *(const float4*)(W1 + k * 128 + c0);
#pragma unroll
            for (int r = 0; r < 8; ++r) {
                float x = xs[(r0 + r) * 128 + k];
                acc[r][0] = fmaf(x, w.x, acc[r][0]);
                acc[r][1] = fmaf(x, w.y, acc[r][1]);
                acc[r][2] = fmaf(x, w.z, acc[r][2]);
                acc[r][3] = fmaf(x, w.w, acc[r][3]);
            }
        }
        float4 alv = *(const float4*)(al1 + c0);
        float4 arv = *(const float4*)(ar1 + c0);
#pragma unroll
        for (int r = 0; r < 8; ++r) {
            int row = row0 + r0 + r;
            if (row < N) {
                ushort4 fb;
                fb.x = f2bf(acc[r][0]);
                fb.y = f2bf(acc[r][1]);
                fb.z = f2bf(acc[r][2]);
                fb.w = f2bf(acc[r][3]);
                *(ushort4*)(feat1b + (size_t)row * 128 + c0) = fb;
                float pl = acc[r][0] * alv.x + acc[r][1] * alv.y + acc[r][2] * alv.z +
                           acc[r][3] * alv.w;
                float pr = acc[r][0] * arv.x + acc[r][1] * arv.y + acc[r][2] * arv.z +
                           acc[r][3] * arv.w;
#pragma unroll
                for (int off = 4; off >= 1; off >>= 1) {
                    pl += __shfl_xor(pl, off, 32);
                    pr += __shfl_xor(pr, off, 32);
                }
                if ((lane & 7) == 0) {
                    el1[row * 4 + (lane >> 3)] = pl;
                    er1[row * 4 + (lane >> 3)] = pr;
                }
            }
        }
    }
}

__global__ __launch_bounds__(64) void bucketD_kernel(const unsigned* __restrict__ tmp,
                                                     const int* __restrict__ bucket_base,
                                                     int* __restrict__ srcs,
                                                     int* __restrict__ row_start,
                                                     int N, int NB) {
    __shared__ unsigned sval[DCAP];
    __shared__ int ssrc[DCAP];
    __shared__ int dh[64], dex[64], dcur[64];
    const int b = blockIdx.x;
    const int tid = threadIdx.x;  // one wave
    const int gb = bucket_base[b], ge = bucket_base[b + 1];
    const int cnt = ge - gb;
    dh[tid] = 0;
    __syncthreads();
    if (cnt <= DCAP) {
        for (int i = tid; i < cnt; i += 64) {
            unsigned v = tmp[gb + i];
            sval[i] = v;
            atomicAdd(&dh[(v >> 16) & 63], 1);
        }
        __syncthreads();
        int v = dh[tid], inc = v;
        for (int off = 1; off < 64; off <<= 1) {
            int t = __shfl_up(inc, off, 64);
            if (tid >= off) inc += t;
        }
        int ex = inc - v;
        dex[tid] = ex;
        dcur[tid] = 0;
        __syncthreads();
        for (int i = tid; i < cnt; i += 64) {
            unsigned val = sval[i];
            int dl = (val >> 16) & 63;
            int r = atomicAdd(&dcur[dl], 1);
            ssrc[dex[dl] + r] = (int)(val & 0xFFFFu);
        }
        __syncthreads();
        for (int i = tid; i < cnt; i += 64) srcs[gb + i] = ssrc[i];
        int dglob = b * 64 + tid;
        if (dglob < N) row_start[dglob] = gb + ex;
    } else {
        for (int i = tid; i < cnt; i += 64) atomicAdd(&dh[(tmp[gb + i] >> 16) & 63], 1);
        __syncthreads();
        int v = dh[tid], inc = v;
        for (int off = 1; off < 64; off <<= 1) {
            int t = __shfl_up(inc, off, 64);
            if (tid >= off) inc += t;
        }
        int ex = inc - v;
        dex[tid] = ex;
        dcur[tid] = 0;
        __syncthreads();
        for (int i = tid; i < cnt; i += 64) {
            unsigned val = tmp[gb + i];
            int dl = (val >> 16) & 63;
            int r = atomicAdd(&dcur[dl], 1);
            srcs[gb + dex[dl] + r] = (int)(val & 0xFFFFu);
        }
        int dglob = b * 64 + tid;
        if (dglob < N) row_start[dglob] = gb + ex;
    }
}

// ===========================================================================
// GEMM2 fused: feat2b(bf16) = relu(out1) @ W2; el2/er2 fused.
// 128 rows/block, 256 threads, 8x4 per thread.
// ===========================================================================
__global__ __launch_bounds__(256) void gemm2_fused(const float* __restrict__ out1,
                                                   const float* __restrict__ W2,
                                                   const float* __restrict__ al2,
                                                   const float* __restrict__ ar2,
                                                   unsigned short* __restrict__ feat2b,
                                                   float* __restrict__ el2,
                                                   float* __restrict__ er2, int N) {
    __shared__ float xs[128 * 128];  // 64 KB
    const int tid = threadIdx.x;
    const int row0 = blockIdx.x * 128;
    {
        const float4* s4 = (const float4*)out1;
        float4* d4 = (float4*)xs;
        int base4 = row0 * 32;
        int tot4 = N * 32;
        for (int i = tid; i < 4096; i += 256)
            if (base4 + i < tot4) {
                float4 v = s4[base4 + i];
                v.x = v.x > 0.f ? v.x : 0.f;
                v.y = v.y > 0.f ? v.y : 0.f;
                v.z = v.z > 0.f ? v.z : 0.f;
                v.w = v.w > 0.f ? v.w : 0.f;
                d4[i] = v;
            }
    }
    __syncthreads();
    const int lane = tid & 15;
    const int c0 = lane * 4;
    const int r0 = (tid >> 4) * 8;
    float acc[8][4] = {};
#pragma unroll 4
    for (int k = 0; k < 128; ++k) {
        float4 w = *(const float4*)(W2 + k * 64 + c0);
#pragma unroll
        for (int r = 0; r < 8; ++r) {
            float x = xs[(r0 + r) * 128 + k];
            acc[r][0] = fmaf(x, w.x, acc[r][0]);
            acc[r][1] = fmaf(x, w.y, acc[r][1]);
            acc[r][2] = fmaf(x, w.z, acc[r][2]);
            acc[r][3] = fmaf(x, w.w, acc[r][3]);
        }
    }
    float4 alv = *(const float4*)(al2 + c0);
    float4 arv = *(const float4*)(ar2 + c0);
#pragma unroll
    for (int r = 0; r < 8; ++r) {
        int row = row0 + r0 + r;
        if (row < N) {
            ushort4 fb;
            fb.x = f2bf(acc[r][0]);
            fb.y = f2bf(acc[r][1]);
            fb.z = f2bf(acc[r][2]);
            fb.w = f2bf(acc[r][3]);
            *(ushort4*)(feat2b + (size_t)row * 64 + c0) = fb;
            float pl = acc[r][0] * alv.x + acc[r][1] * alv.y + acc[r][2] * alv.z +
                       acc[r][3] * alv.w;
            float pr = acc[r][0] * arv.x + acc[r][1] * arv.y + acc[r][2] * arv.z +
                       acc[r][3] * arv.w;
#pragma unroll
            for (int off = 8; off >= 1; off >>= 1) {
                pl += __shfl_xor(pl, off, 16);
                pr += __shfl_xor(pr, off, 16);
            }
            if (lane == 0) {
                el2[row] = pl;
                er2[row] = pr;
            }
        }
    }
}

// ===========================================================================
// Gather layer 1: 256-thread blocks, one dst per wave (wave-synchronous LDS),
// half-wave edge split (even/odd edges), shfl_xor(32) combine.
// ===========================================================================
__global__ __launch_bounds__(256) void gather1_kernel(const int* __restrict__ row_start,
                                                      const int* __restrict__ srcs,
                                                      const float* __restrict__ el1,
                                                      const float* __restrict__ er1,
                                                      const unsigned short* __restrict__ feat1b,
                                                      const float* __restrict__ b1,
                                                      float* __restrict__ out1, int N) {
    __shared__ int s_sh[4][64];
    __shared__ float a_sh[4][256];
    const int tid = threadIdx.x;
    const int w = tid >> 6;       // wave in block
    const int lane = tid & 63;
    const int d = blockIdx.x * 4 + w;
    if (d >= N) return;
    const int beg = row_start[d], end = row_start[d + 1];
    const int half = lane >> 5;   // 0: even edges, 1: odd edges
    const int l32 = lane & 31;
    const int c0 = l32 * 4;       // 4 cols per lane (32 lanes cover 128)
    const int h = l32 >> 3;       // head of this lane's columns
    float4 er4 = *(const float4*)(er1 + (size_t)d * 4);
    float acc0 = 0.f, acc1 = 0.f, acc2 = 0.f, acc3 = 0.f;
    float bcc0 = 0.f, bcc1 = 0.f, bcc2 = 0.f, bcc3 = 0.f;
    float den = 0.f;
    for (int k0 = beg; k0 < end; k0 += 64) {
        const int M = min(64, end - k0);
        if (lane < M) {
            int s = srcs[k0 + lane];
            s_sh[w][lane] = s;
            float4 el4 = *(const float4*)(el1 + (size_t)s * 4);
            float v0 = el4.x + er4.x;
            float v1 = el4.y + er4.y;
            float v2 = el4.z + er4.z;
            float v3 = el4.w + er4.w;
            v0 = v0 > 0.f ? v0 : NEG_SLOPE * v0;
            v1 = v1 > 0.f ? v1 : NEG_SLOPE * v1;
            v2 = v2 > 0.f ? v2 : NEG_SLOPE * v2;
            v3 = v3 > 0.f ? v3 : NEG_SLOPE * v3;
            a_sh[w][lane * 4 + 0] = __expf(v0);
            a_sh[w][lane * 4 + 1] = __expf(v1);
            a_sh[w][lane * 4 + 2] = __expf(v2);
            a_sh[w][lane * 4 + 3] = __expf(v3);
        }
        wave_lds_fence();
        int e = half;
        for (; e + 2 < M; e += 4) {  // process e and e+2 (this half's stride-2 walk)
            int s0 = s_sh[w][e], s1 = s_sh[w][e + 2];
            float a0 = a_sh[w][e * 4 + h];
            float a1 = a_sh[w][(e + 2) * 4 + h];
            ushort4 f0 = *(const ushort4*)(feat1b + (size_t)s0 * 128 + c0);
            ushort4 f1 = *(const ushort4*)(feat1b + (size_t)s1 * 128 + c0);
            den += a0 + a1;
            acc0 = fmaf(bf2f(f0.x), a0, acc0);
            acc1 = fmaf(bf2f(f0.y), a0, acc1);
            acc2 = fmaf(bf2f(f0.z), a0, acc2);
            acc3 = fmaf(bf2f(f0.w), a0, acc3);
            bcc0 = fmaf(bf2f(f1.x), a1, bcc0);
            bcc1 = fmaf(bf2f(f1.y), a1, bcc1);
            bcc2 = fmaf(bf2f(f1.z), a1, bcc2);
            bcc3 = fmaf(bf2f(f1.w), a1, bcc3);
        }
        if (e < M) {
            int s0 = s_sh[w][e];
            float a0 = a_sh[w][e * 4 + h];
            ushort4 f0 = *(const ushort4*)(feat1b + (size_t)s0 * 128 + c0);
            den += a0;
            acc0 = fmaf(bf2f(f0.x), a0, acc0);
            acc1 = fmaf(bf2f(f0.y), a0, acc1);
            acc2 = fmaf(bf2f(f0.z), a0, acc2);
            acc3 = fmaf(bf2f(f0.w), a0, acc3);
        }
        wave_lds_fence();
    }
    acc0 += bcc0;
    acc1 += bcc1;
    acc2 += bcc2;
    acc3 += bcc3;
    // combine the two halves (they hold the same columns, different edges)
    acc0 += __shfl_xor(acc0, 32, 64);
    acc1 += __shfl_xor(acc1, 32, 64);
    acc2 += __shfl_xor(acc2, 32, 64);
    acc3 += __shfl_xor(acc3, 32, 64);
    den += __shfl_xor(den, 32, 64);
    if (half == 0) {
        float inv = (end > beg) ? 1.f / den : 0.f;
        float4 bv = *(const float4*)(b1 + c0);
        *(float4*)(out1 + (size_t)d * 128 + c0) =
            make_float4(acc0 * inv + bv.x, acc1 * inv + bv.y,
                        acc2 * inv + bv.z, acc3 * inv + bv.w);
    }
}

// ===========================================================================
// Gather layer 2: same structure. H=1, D=64; 2 cols/lane per half.
// ===========================================================================
__global__ __launch_bounds__(256) void gather2_kernel(const int* __restrict__ row_start,
                                                      const int* __restrict__ srcs,
                                                      const float* __restrict__ el2,
                                                      const float* __restrict__ er2,
                                                      const unsigned short* __restrict__ feat2b,
                                                      const float* __restrict__ b2,
                                                      float* __restrict__ out2, int N) {
    __shared__ int s_sh[4][64];
    __shared__ float a_sh[4][64];
    const int tid = threadIdx.x;
    const int w = tid >> 6;
    const int lane = tid & 63;
    const int d = blockIdx.x * 4 + w;
    if (d >= N) return;
    const int beg = row_start[d], end = row_start[d + 1];
    const int half = lane >> 5;
    const int l32 = lane & 31;
    const int c0 = l32 * 2;  // 2 cols per lane (32 lanes cover 64)
    const float er_d = er2[d];
    float acc0 = 0.f, acc1 = 0.f, bcc0 = 0.f, bcc1 = 0.f, den = 0.f;
    for (int k0 = beg; k0 < end; k0 += 64) {
        const int M = min(64, end - k0);
        if (lane < M) {
            int s = srcs[k0 + lane];
            s_sh[w][lane] = s;
            float v = el2[s] + er_d;
            v = v > 0.f ? v : NEG_SLOPE * v;
            a_sh[w][lane] = __expf(v);
        }
        wave_lds_fence();
        int e = half;
        for (; e + 2 < M; e += 4) {
            int s0 = s_sh[w][e], s1 = s_sh[w][e + 2];
            float a0 = a_sh[w][e], a1 = a_sh[w][e + 2];
            ushort2 f0 = *(const ushort2*)(feat2b + (size_t)s0 * 64 + c0);
            ushort2 f1 = *(const ushort2*)(feat2b + (size_t)s1 * 64 + c0);
            den += a0 + a1;
            acc0 = fmaf(bf2f(f0.x), a0, acc0);
            acc1 = fmaf(bf2f(f0.y), a0, acc1);
            bcc0 = fmaf(bf2f(f1.x), a1, bcc0);
            bcc1 = fmaf(bf2f(f1.y), a1, bcc1);
        }
        if (e < M) {
            int s0 = s_sh[w][e];
            float a0 = a_sh[w][e];
            ushort2 f0 = *(const ushort2*)(feat2b + (size_t)s0 * 64 + c0);
            den += a0;
            acc0 = fmaf(bf2f(f0.x), a0, acc0);
            acc1 = fmaf(bf2f(f0.y), a0, acc1);
        }
        wave_lds_fence();
    }
    acc0 += bcc0;
    acc1 += bcc1;
    acc0 += __shfl_xor(acc0, 32, 64);
    acc1 += __shfl_xor(acc1, 32, 64);
    den += __shfl_xor(den, 32, 64);
    if (half == 0) {
        float inv = (end > beg) ? 1.f / den : 0.f;
        *(float2*)(out2 + (size_t)d * 64 + c0) =
            make_float2(acc0 * inv + b2[c0], acc1 * inv + b2[c0 + 1]);
    }
}

// ===========================================================================
extern "C" void kernel_launch(void* const* d_in, const int* in_sizes, int n_in,
                              void* d_out, int out_size, void* d_ws, size_t ws_size,
                              hipStream_t stream) {
    const float* h   = (const float*)d_in[0];
    const int*   src = (const int*)d_in[1];
    const int*   dst = (const int*)d_in[2];
    const float* W1  = (const float*)d_in[3];
    const float* al1 = (const float*)d_in[4];
    const float* ar1 = (const float*)d_in[5];
    const float* b1  = (const float*)d_in[6];
    const float* W2  = (const float*)d_in[7];
    const float* al2 = (const float*)d_in[8];
    const float* ar2 = (const float*)d_in[9];
    const float* b2  = (const float*)d_in[10];

    const int N = in_sizes[0] / 128;  // 50000 (pack assumes N <= 65536)
    const int E = in_sizes[1];        // 800000
    const int NB = (N + 63) >> 6;     // 782 buckets

    char* ws = (char*)d_ws;
    size_t off = 0;
    auto alloc = [&](size_t elems) -> void* {  // elems are 4-byte units
        void* p = (void*)(ws + off);
        off += ((elems * 4 + 255) / 256) * 256;
        return p;
    };
    int* bucket_cnt    = (int*)alloc(NB);
    int* bucket_base   = (int*)alloc(NB + 1);
    int* bucket_cursor = (int*)alloc(NB);
    unsigned* tmp      = (unsigned*)alloc(E);
    int* srcs          = (int*)alloc(E);
    int* row_start     = (int*)alloc(N + 1);
    float* el1   = (float*)alloc((size_t)N * 4);
    float* er1   = (float*)alloc((size_t)N * 4);
    unsigned short* feat1b = (unsigned short*)alloc((size_t)N * 64);  // N*128 bf16
    float* out1  = (float*)alloc((size_t)N * 128);
    float* el2   = (float*)alloc(N);
    float* er2   = (float*)alloc(N);
    unsigned short* feat2b = (unsigned short*)alloc((size_t)N * 32);  // N*64 bf16
    float* out2  = (float*)d_out;

    const int nchunks = (E + CH - 1) / CH;
    const int gemm1_blocks = (N + 63) / 64;

    // --- CSR build + layer-1 GEMM (partition overlapped with GEMM) ---
    zerob_kernel<<<(NB + 255) / 256, 256, 0, stream>>>(bucket_cnt, NB);
    bucketA_kernel<<<nchunks, 256, 0, stream>>>(dst, bucket_cnt, E, NB);
    bucketB_kernel<<<1, 1024, 0, stream>>>(bucket_cnt, bucket_base, bucket_cursor,
                                           row_start, N, NB, E);
    csrC_gemm1_kernel<<<nchunks + gemm1_blocks, 256, 0, stream>>>(
        src, dst, bucket_cursor, tmp, E, NB, nchunks, h, W1, al1, ar1, feat1b, el1,
        er1, N);
    bucketD_kernel<<<NB, 64, 0, stream>>>(tmp, bucket_base, srcs, row_start, N, NB);

    // --- layer 1 gather ---
    gather1_kernel<<<(N + 3) / 4, 256, 0, stream>>>(row_start, srcs, el1, er1, feat1b,
                                                    b1, out1, N);

    // --- layer 2 ---
    gemm2_fused<<<(N + 127) / 128, 256, 0, stream>>>(out1, W2, al2, ar2, feat2b, el2,
                                                     er2, N);
    gather2_kernel<<<(N + 3) / 4, 256, 0, stream>>>(row_start, srcs, el2, er2, feat2b,
                                                    b2, out2, N);
}

// Round 8
// 222.465 us; speedup vs baseline: 4.4094x; 1.0423x over previous
//
#include <hip/hip_runtime.h>

#define NEG_SLOPE 0.2f
#define CH 4096      // edges per partition block
#define DCAP 2048    // max edges per bucket handled via LDS fast path

__device__ inline unsigned short f2bf(float f) {
    unsigned u = __float_as_uint(f);
    unsigned r = (u + 0x7FFFu + ((u >> 16) & 1u)) >> 16;
    return (unsigned short)r;
}
__device__ inline float bf2f(unsigned short s) {
    return __uint_as_float(((unsigned)s) << 16);
}
__device__ inline void wave_lds_fence() {
    asm volatile("s_waitcnt lgkmcnt(0)" ::: "memory");
}

// ===========================================================================
// CSR build via write-combined radix partition. bucket = dst>>6 (64 dsts each).
// Packed edge: (bucket<<22) | ((dst&63)<<16) | src   (requires N <= 65536)
// ===========================================================================
__global__ __launch_bounds__(256) void bucketA_kernel(const int* __restrict__ dst,
                                                      int* __restrict__ bucket_cnt,
                                                      int E, int NB) {
    __shared__ int lh[1024];
    const int tid = threadIdx.x;
    for (int i = tid; i < 1024; i += 256) lh[i] = 0;
    __syncthreads();
    const int base = blockIdx.x * CH;
    const int cnt = min(CH, E - base);
    for (int i = tid; i < cnt; i += 256) atomicAdd(&lh[dst[base + i] >> 6], 1);
    __syncthreads();
    for (int b = tid; b < NB; b += 256)
        if (lh[b]) atomicAdd(&bucket_cnt[b], lh[b]);
}

__global__ __launch_bounds__(1024) void bucketB_kernel(const int* __restrict__ bucket_cnt,
                                                       int* __restrict__ bucket_base,
                                                       int* __restrict__ bucket_cursor,
                                                       int* __restrict__ row_start,
                                                       int N, int NB, int E) {
    __shared__ int sh[1024];
    const int tid = threadIdx.x;
    int v = (tid < NB) ? bucket_cnt[tid] : 0;
    sh[tid] = v;
    __syncthreads();
    for (int off = 1; off < 1024; off <<= 1) {
        int t = (tid >= off) ? sh[tid - off] : 0;
        __syncthreads();
        sh[tid] += t;
        __syncthreads();
    }
    int ex = sh[tid] - v;
    if (tid < NB) {
        bucket_base[tid] = ex;
        bucket_cursor[tid] = ex;
    }
    if (tid == NB - 1) bucket_base[NB] = ex + v;  // == E
    if (tid == 0) row_start[N] = E;
}

// ===========================================================================
// FUSED: bucketC (edge partition) || gemm1 (feat1b = h@W1 + el1/er1).
// ===========================================================================
__global__ __launch_bounds__(256) void csrC_gemm1_kernel(
    const int* __restrict__ src, const int* __restrict__ dst,
    int* __restrict__ bucket_cursor, unsigned* __restrict__ tmp, int E, int NB,
    int nchunks, const float* __restrict__ h, const float* __restrict__ W1,
    const float* __restrict__ al1, const float* __restrict__ ar1,
    unsigned short* __restrict__ feat1b, float* __restrict__ el1,
    float* __restrict__ er1, int N) {
    __shared__ __align__(16) int smem[8448];  // 33 KB union
    const int tid = threadIdx.x;
    if ((int)blockIdx.x < nchunks) {
        // ---------------- bucketC body ----------------
        int* lh = smem;                               // 1024
        int* lex = smem + 1024;                       // 1024
        int* lcur = smem + 2048;                      // 1024
        int* gbase_sh = smem + 3072;                  // 1024
        int* psum = smem + 4096;                      // 256
        unsigned* sortedv = (unsigned*)(smem + 4352); // 4096
        const int base_e = blockIdx.x * CH;
        const int cnt_e = min(CH, E - base_e);
        for (int i = tid; i < 1024; i += 256) lh[i] = 0;
        __syncthreads();
        for (int i = tid; i < cnt_e; i += 256) atomicAdd(&lh[dst[base_e + i] >> 6], 1);
        __syncthreads();
        int s0 = lh[tid * 4], s1 = lh[tid * 4 + 1], s2 = lh[tid * 4 + 2], s3 = lh[tid * 4 + 3];
        int tot = s0 + s1 + s2 + s3;
        psum[tid] = tot;
        __syncthreads();
        for (int off = 1; off < 256; off <<= 1) {
            int t = (tid >= off) ? psum[tid - off] : 0;
            __syncthreads();
            psum[tid] += t;
            __syncthreads();
        }
        int ebase = psum[tid] - tot;
        lex[tid * 4] = ebase;
        lex[tid * 4 + 1] = ebase + s0;
        lex[tid * 4 + 2] = ebase + s0 + s1;
        lex[tid * 4 + 3] = ebase + s0 + s1 + s2;
        __syncthreads();
        for (int b = tid; b < NB; b += 256) {
            int c = lh[b];
            gbase_sh[b] = c ? atomicAdd(&bucket_cursor[b], c) : 0;
            lcur[b] = 0;
        }
        __syncthreads();
        for (int i = tid; i < cnt_e; i += 256) {
            int e = base_e + i;
            int d = dst[e];
            unsigned b = (unsigned)d >> 6;
            int r = atomicAdd(&lcur[b], 1);
            sortedv[lex[b] + r] =
                (b << 22) | ((unsigned)(d & 63) << 16) | (unsigned)(src[e] & 0xFFFF);
        }
        __syncthreads();
        for (int i = tid; i < cnt_e; i += 256) {
            unsigned v = sortedv[i];
            int b = v >> 22;
            tmp[gbase_sh[b] + (i - lex[b])] = v;
        }
    } else {
        // ---------------- gemm1 body ----------------
        float* xs = (float*)smem;  // 64*128 floats = 32 KB
        const int row0 = ((int)blockIdx.x - nchunks) * 64;
        {
            const float4* s4 = (const float4*)h;
            float4* d4 = (float4*)xs;
            int base4 = row0 * 32;
            int tot4 = N * 32;
            for (int i = tid; i < 2048; i += 256)
                if (base4 + i < tot4) d4[i] = s4[base4 + i];
        }
        __syncthreads();
        const int lane = tid & 31;
        const int c0 = lane * 4;
        const int r0 = (tid >> 5) * 8;
        float acc[8][4] = {};
#pragma unroll 4
        for (int k = 0; k < 128; ++k) {
            float4 w = *(const float4*)(W1 + k * 128 + c0);
#pragma unroll
            for (int r = 0; r < 8; ++r) {
                float x = xs[(r0 + r) * 128 + k];
                acc[r][0] = fmaf(x, w.x, acc[r][0]);
                acc[r][1] = fmaf(x, w.y, acc[r][1]);
                acc[r][2] = fmaf(x, w.z, acc[r][2]);
                acc[r][3] = fmaf(x, w.w, acc[r][3]);
            }
        }
        float4 alv = *(const float4*)(al1 + c0);
        float4 arv = *(const float4*)(ar1 + c0);
#pragma unroll
        for (int r = 0; r < 8; ++r) {
            int row = row0 + r0 + r;
            if (row < N) {
                ushort4 fb;
                fb.x = f2bf(acc[r][0]);
                fb.y = f2bf(acc[r][1]);
                fb.z = f2bf(acc[r][2]);
                fb.w = f2bf(acc[r][3]);
                *(ushort4*)(feat1b + (size_t)row * 128 + c0) = fb;
                float pl = acc[r][0] * alv.x + acc[r][1] * alv.y + acc[r][2] * alv.z +
                           acc[r][3] * alv.w;
                float pr = acc[r][0] * arv.x + acc[r][1] * arv.y + acc[r][2] * arv.z +
                           acc[r][3] * arv.w;
#pragma unroll
                for (int off = 4; off >= 1; off >>= 1) {
                    pl += __shfl_xor(pl, off, 32);
                    pr += __shfl_xor(pr, off, 32);
                }
                if ((lane & 7) == 0) {
                    el1[row * 4 + (lane >> 3)] = pl;
                    er1[row * 4 + (lane >> 3)] = pr;
                }
            }
        }
    }
}

// ===========================================================================
// bucketD: per-bucket counting sort by dst low bits. 256 threads/block.
// ===========================================================================
__global__ __launch_bounds__(256) void bucketD_kernel(const unsigned* __restrict__ tmp,
                                                      const int* __restrict__ bucket_base,
                                                      int* __restrict__ srcs,
                                                      int* __restrict__ row_start,
                                                      int N, int NB) {
    __shared__ unsigned sval[DCAP];
    __shared__ int ssrc[DCAP];
    __shared__ int dh[64], dex[64], dcur[64];
    const int b = blockIdx.x;
    const int tid = threadIdx.x;  // 0..255
    const int gb = bucket_base[b], ge = bucket_base[b + 1];
    const int cnt = ge - gb;
    if (tid < 64) dh[tid] = 0;
    __syncthreads();
    if (cnt <= DCAP) {
        for (int i = tid; i < cnt; i += 256) {
            unsigned v = tmp[gb + i];
            sval[i] = v;
            atomicAdd(&dh[(v >> 16) & 63], 1);
        }
        __syncthreads();
        if (tid < 64) {
            int v = dh[tid], inc = v;
            for (int off = 1; off < 64; off <<= 1) {
                int t = __shfl_up(inc, off, 64);
                if (tid >= off) inc += t;
            }
            dex[tid] = inc - v;
            dcur[tid] = 0;
            int dglob = b * 64 + tid;
            if (dglob < N) row_start[dglob] = gb + inc - v;
        }
        __syncthreads();
        for (int i = tid; i < cnt; i += 256) {
            unsigned val = sval[i];
            int dl = (val >> 16) & 63;
            int r = atomicAdd(&dcur[dl], 1);
            ssrc[dex[dl] + r] = (int)(val & 0xFFFFu);
        }
        __syncthreads();
        for (int i = tid; i < cnt; i += 256) srcs[gb + i] = ssrc[i];
    } else {
        // robust fallback (never hit for this input)
        for (int i = tid; i < cnt; i += 256) atomicAdd(&dh[(tmp[gb + i] >> 16) & 63], 1);
        __syncthreads();
        if (tid < 64) {
            int v = dh[tid], inc = v;
            for (int off = 1; off < 64; off <<= 1) {
                int t = __shfl_up(inc, off, 64);
                if (tid >= off) inc += t;
            }
            dex[tid] = inc - v;
            dcur[tid] = 0;
            int dglob = b * 64 + tid;
            if (dglob < N) row_start[dglob] = gb + inc - v;
        }
        __syncthreads();
        for (int i = tid; i < cnt; i += 256) {
            unsigned val = tmp[gb + i];
            int dl = (val >> 16) & 63;
            int r = atomicAdd(&dcur[dl], 1);
            srcs[gb + dex[dl] + r] = (int)(val & 0xFFFFu);
        }
    }
}

// ===========================================================================
// GEMM2: feat2b(bf16) = out1b(relu'd bf16) @ W2; el2/er2 fused.
// 128 rows/block, 256 threads, 8x4 per thread.
// ===========================================================================
__global__ __launch_bounds__(256) void gemm2_fused(const unsigned short* __restrict__ out1b,
                                                   const float* __restrict__ W2,
                                                   const float* __restrict__ al2,
                                                   const float* __restrict__ ar2,
                                                   unsigned short* __restrict__ feat2b,
                                                   float* __restrict__ el2,
                                                   float* __restrict__ er2, int N) {
    __shared__ float xs[128 * 128];  // 64 KB
    const int tid = threadIdx.x;
    const int row0 = blockIdx.x * 128;
    {
        const uint4* s8 = (const uint4*)out1b;  // 8 bf16 per uint4
        int base8 = row0 * 16;
        int tot8 = N * 16;
        for (int i = tid; i < 2048; i += 256)
            if (base8 + i < tot8) {
                uint4 v = s8[base8 + i];
                float* o = xs + i * 8;
                o[0] = bf2f((unsigned short)(v.x & 0xFFFF));
                o[1] = bf2f((unsigned short)(v.x >> 16));
                o[2] = bf2f((unsigned short)(v.y & 0xFFFF));
                o[3] = bf2f((unsigned short)(v.y >> 16));
                o[4] = bf2f((unsigned short)(v.z & 0xFFFF));
                o[5] = bf2f((unsigned short)(v.z >> 16));
                o[6] = bf2f((unsigned short)(v.w & 0xFFFF));
                o[7] = bf2f((unsigned short)(v.w >> 16));
            }
    }
    __syncthreads();
    const int lane = tid & 15;
    const int c0 = lane * 4;
    const int r0 = (tid >> 4) * 8;
    float acc[8][4] = {};
#pragma unroll 4
    for (int k = 0; k < 128; ++k) {
        float4 w = *(const float4*)(W2 + k * 64 + c0);
#pragma unroll
        for (int r = 0; r < 8; ++r) {
            float x = xs[(r0 + r) * 128 + k];
            acc[r][0] = fmaf(x, w.x, acc[r][0]);
            acc[r][1] = fmaf(x, w.y, acc[r][1]);
            acc[r][2] = fmaf(x, w.z, acc[r][2]);
            acc[r][3] = fmaf(x, w.w, acc[r][3]);
        }
    }
    float4 alv = *(const float4*)(al2 + c0);
    float4 arv = *(const float4*)(ar2 + c0);
#pragma unroll
    for (int r = 0; r < 8; ++r) {
        int row = row0 + r0 + r;
        if (row < N) {
            ushort4 fb;
            fb.x = f2bf(acc[r][0]);
            fb.y = f2bf(acc[r][1]);
            fb.z = f2bf(acc[r][2]);
            fb.w = f2bf(acc[r][3]);
            *(ushort4*)(feat2b + (size_t)row * 64 + c0) = fb;
            float pl = acc[r][0] * alv.x + acc[r][1] * alv.y + acc[r][2] * alv.z +
                       acc[r][3] * alv.w;
            float pr = acc[r][0] * arv.x + acc[r][1] * arv.y + acc[r][2] * arv.z +
                       acc[r][3] * arv.w;
#pragma unroll
            for (int off = 8; off >= 1; off >>= 1) {
                pl += __shfl_xor(pl, off, 16);
                pr += __shfl_xor(pr, off, 16);
            }
            if (lane == 0) {
                el2[row] = pl;
                er2[row] = pr;
            }
        }
    }
}

// ===========================================================================
// Gather layer 1: 256-thread blocks, one dst per wave (wave-synchronous LDS),
// half-wave edge split. Epilogue: +bias, ReLU, bf16 store (layer-2 input).
// ===========================================================================
__global__ __launch_bounds__(256) void gather1_kernel(const int* __restrict__ row_start,
                                                      const int* __restrict__ srcs,
                                                      const float* __restrict__ el1,
                                                      const float* __restrict__ er1,
                                                      const unsigned short* __restrict__ feat1b,
                                                      const float* __restrict__ b1,
                                                      unsigned short* __restrict__ out1b,
                                                      int N) {
    __shared__ int s_sh[4][64];
    __shared__ float a_sh[4][256];
    const int tid = threadIdx.x;
    const int w = tid >> 6;       // wave in block
    const int lane = tid & 63;
    const int d = blockIdx.x * 4 + w;
    if (d >= N) return;
    const int beg = row_start[d], end = row_start[d + 1];
    const int half = lane >> 5;   // 0: even edges, 1: odd edges
    const int l32 = lane & 31;
    const int c0 = l32 * 4;       // 4 cols per lane
    const int h = l32 >> 3;       // head of this lane's columns
    float4 er4 = *(const float4*)(er1 + (size_t)d * 4);
    float acc0 = 0.f, acc1 = 0.f, acc2 = 0.f, acc3 = 0.f;
    float bcc0 = 0.f, bcc1 = 0.f, bcc2 = 0.f, bcc3 = 0.f;
    float den = 0.f;
    for (int k0 = beg; k0 < end; k0 += 64) {
        const int M = min(64, end - k0);
        if (lane < M) {
            int s = srcs[k0 + lane];
            s_sh[w][lane] = s;
            float4 el4 = *(const float4*)(el1 + (size_t)s * 4);
            float v0 = el4.x + er4.x;
            float v1 = el4.y + er4.y;
            float v2 = el4.z + er4.z;
            float v3 = el4.w + er4.w;
            v0 = v0 > 0.f ? v0 : NEG_SLOPE * v0;
            v1 = v1 > 0.f ? v1 : NEG_SLOPE * v1;
            v2 = v2 > 0.f ? v2 : NEG_SLOPE * v2;
            v3 = v3 > 0.f ? v3 : NEG_SLOPE * v3;
            a_sh[w][lane * 4 + 0] = __expf(v0);
            a_sh[w][lane * 4 + 1] = __expf(v1);
            a_sh[w][lane * 4 + 2] = __expf(v2);
            a_sh[w][lane * 4 + 3] = __expf(v3);
        }
        wave_lds_fence();
        int e = half;
        for (; e + 2 < M; e += 4) {
            int s0 = s_sh[w][e], s1 = s_sh[w][e + 2];
            float a0 = a_sh[w][e * 4 + h];
            float a1 = a_sh[w][(e + 2) * 4 + h];
            ushort4 f0 = *(const ushort4*)(feat1b + (size_t)s0 * 128 + c0);
            ushort4 f1 = *(const ushort4*)(feat1b + (size_t)s1 * 128 + c0);
            den += a0 + a1;
            acc0 = fmaf(bf2f(f0.x), a0, acc0);
            acc1 = fmaf(bf2f(f0.y), a0, acc1);
            acc2 = fmaf(bf2f(f0.z), a0, acc2);
            acc3 = fmaf(bf2f(f0.w), a0, acc3);
            bcc0 = fmaf(bf2f(f1.x), a1, bcc0);
            bcc1 = fmaf(bf2f(f1.y), a1, bcc1);
            bcc2 = fmaf(bf2f(f1.z), a1, bcc2);
            bcc3 = fmaf(bf2f(f1.w), a1, bcc3);
        }
        if (e < M) {
            int s0 = s_sh[w][e];
            float a0 = a_sh[w][e * 4 + h];
            ushort4 f0 = *(const ushort4*)(feat1b + (size_t)s0 * 128 + c0);
            den += a0;
            acc0 = fmaf(bf2f(f0.x), a0, acc0);
            acc1 = fmaf(bf2f(f0.y), a0, acc1);
            acc2 = fmaf(bf2f(f0.z), a0, acc2);
            acc3 = fmaf(bf2f(f0.w), a0, acc3);
        }
        wave_lds_fence();
    }
    acc0 += bcc0;
    acc1 += bcc1;
    acc2 += bcc2;
    acc3 += bcc3;
    acc0 += __shfl_xor(acc0, 32, 64);
    acc1 += __shfl_xor(acc1, 32, 64);
    acc2 += __shfl_xor(acc2, 32, 64);
    acc3 += __shfl_xor(acc3, 32, 64);
    den += __shfl_xor(den, 32, 64);
    if (half == 0) {
        float inv = (end > beg) ? 1.f / den : 0.f;
        float4 bv = *(const float4*)(b1 + c0);
        float r0v = fmaxf(acc0 * inv + bv.x, 0.f);
        float r1v = fmaxf(acc1 * inv + bv.y, 0.f);
        float r2v = fmaxf(acc2 * inv + bv.z, 0.f);
        float r3v = fmaxf(acc3 * inv + bv.w, 0.f);
        ushort4 o;
        o.x = f2bf(r0v);
        o.y = f2bf(r1v);
        o.z = f2bf(r2v);
        o.w = f2bf(r3v);
        *(ushort4*)(out1b + (size_t)d * 128 + c0) = o;
    }
}

// ===========================================================================
// Gather layer 2: same structure. H=1, D=64; 2 cols/lane per half.
// ===========================================================================
__global__ __launch_bounds__(256) void gather2_kernel(const int* __restrict__ row_start,
                                                      const int* __restrict__ srcs,
                                                      const float* __restrict__ el2,
                                                      const float* __restrict__ er2,
                                                      const unsigned short* __restrict__ feat2b,
                                                      const float* __restrict__ b2,
                                                      float* __restrict__ out2, int N) {
    __shared__ int s_sh[4][64];
    __shared__ float a_sh[4][64];
    const int tid = threadIdx.x;
    const int w = tid >> 6;
    const int lane = tid & 63;
    const int d = blockIdx.x * 4 + w;
    if (d >= N) return;
    const int beg = row_start[d], end = row_start[d + 1];
    const int half = lane >> 5;
    const int l32 = lane & 31;
    const int c0 = l32 * 2;
    const float er_d = er2[d];
    float acc0 = 0.f, acc1 = 0.f, bcc0 = 0.f, bcc1 = 0.f, den = 0.f;
    for (int k0 = beg; k0 < end; k0 += 64) {
        const int M = min(64, end - k0);
        if (lane < M) {
            int s = srcs[k0 + lane];
            s_sh[w][lane] = s;
            float v = el2[s] + er_d;
            v = v > 0.f ? v : NEG_SLOPE * v;
            a_sh[w][lane] = __expf(v);
        }
        wave_lds_fence();
        int e = half;
        for (; e + 2 < M; e += 4) {
            int s0 = s_sh[w][e], s1 = s_sh[w][e + 2];
            float a0 = a_sh[w][e], a1 = a_sh[w][e + 2];
            ushort2 f0 = *(const ushort2*)(feat2b + (size_t)s0 * 64 + c0);
            ushort2 f1 = *(const ushort2*)(feat2b + (size_t)s1 * 64 + c0);
            den += a0 + a1;
            acc0 = fmaf(bf2f(f0.x), a0, acc0);
            acc1 = fmaf(bf2f(f0.y), a0, acc1);
            bcc0 = fmaf(bf2f(f1.x), a1, bcc0);
            bcc1 = fmaf(bf2f(f1.y), a1, bcc1);
        }
        if (e < M) {
            int s0 = s_sh[w][e];
            float a0 = a_sh[w][e];
            ushort2 f0 = *(const ushort2*)(feat2b + (size_t)s0 * 64 + c0);
            den += a0;
            acc0 = fmaf(bf2f(f0.x), a0, acc0);
            acc1 = fmaf(bf2f(f0.y), a0, acc1);
        }
        wave_lds_fence();
    }
    acc0 += bcc0;
    acc1 += bcc1;
    acc0 += __shfl_xor(acc0, 32, 64);
    acc1 += __shfl_xor(acc1, 32, 64);
    den += __shfl_xor(den, 32, 64);
    if (half == 0) {
        float inv = (end > beg) ? 1.f / den : 0.f;
        *(float2*)(out2 + (size_t)d * 64 + c0) =
            make_float2(acc0 * inv + b2[c0], acc1 * inv + b2[c0 + 1]);
    }
}

// ===========================================================================
extern "C" void kernel_launch(void* const* d_in, const int* in_sizes, int n_in,
                              void* d_out, int out_size, void* d_ws, size_t ws_size,
                              hipStream_t stream) {
    const float* h   = (const float*)d_in[0];
    const int*   src = (const int*)d_in[1];
    const int*   dst = (const int*)d_in[2];
    const float* W1  = (const float*)d_in[3];
    const float* al1 = (const float*)d_in[4];
    const float* ar1 = (const float*)d_in[5];
    const float* b1  = (const float*)d_in[6];
    const float* W2  = (const float*)d_in[7];
    const float* al2 = (const float*)d_in[8];
    const float* ar2 = (const float*)d_in[9];
    const float* b2  = (const float*)d_in[10];

    const int N = in_sizes[0] / 128;  // 50000 (pack assumes N <= 65536)
    const int E = in_sizes[1];        // 800000
    const int NB = (N + 63) >> 6;     // 782 buckets

    char* ws = (char*)d_ws;
    size_t off = 0;
    auto alloc = [&](size_t elems) -> void* {  // elems are 4-byte units
        void* p = (void*)(ws + off);
        off += ((elems * 4 + 255) / 256) * 256;
        return p;
    };
    int* bucket_cnt    = (int*)alloc(NB);
    int* bucket_base   = (int*)alloc(NB + 1);
    int* bucket_cursor = (int*)alloc(NB);
    unsigned* tmp      = (unsigned*)alloc(E);
    int* srcs          = (int*)alloc(E);
    int* row_start     = (int*)alloc(N + 1);
    float* el1   = (float*)alloc((size_t)N * 4);
    float* er1   = (float*)alloc((size_t)N * 4);
    unsigned short* feat1b = (unsigned short*)alloc((size_t)N * 64);  // N*128 bf16
    unsigned short* out1b  = (unsigned short*)alloc((size_t)N * 64);  // N*128 bf16 (relu'd)
    float* el2   = (float*)alloc(N);
    float* er2   = (float*)alloc(N);
    unsigned short* feat2b = (unsigned short*)alloc((size_t)N * 32);  // N*64 bf16
    float* out2  = (float*)d_out;

    const int nchunks = (E + CH - 1) / CH;
    const int gemm1_blocks = (N + 63) / 64;

    // --- CSR build + layer-1 GEMM ---
    hipMemsetAsync(bucket_cnt, 0, (size_t)NB * 4, stream);
    bucketA_kernel<<<nchunks, 256, 0, stream>>>(dst, bucket_cnt, E, NB);
    bucketB_kernel<<<1, 1024, 0, stream>>>(bucket_cnt, bucket_base, bucket_cursor,
                                           row_start, N, NB, E);
    csrC_gemm1_kernel<<<nchunks + gemm1_blocks, 256, 0, stream>>>(
        src, dst, bucket_cursor, tmp, E, NB, nchunks, h, W1, al1, ar1, feat1b, el1,
        er1, N);
    bucketD_kernel<<<NB, 256, 0, stream>>>(tmp, bucket_base, srcs, row_start, N, NB);

    // --- layer 1 gather (writes relu'd bf16 layer-2 input) ---
    gather1_kernel<<<(N + 3) / 4, 256, 0, stream>>>(row_start, srcs, el1, er1, feat1b,
                                                    b1, out1b, N);

    // --- layer 2 ---
    gemm2_fused<<<(N + 127) / 128, 256, 0, stream>>>(out1b, W2, al2, ar2, feat2b, el2,
                                                     er2, N);
    gather2_kernel<<<(N + 3) / 4, 256, 0, stream>>>(row_start, srcs, el2, er2, feat2b,
                                                    b2, out2, N);
}